// Round 8
// baseline (932.690 us; speedup 1.0000x reference)
//
#include <hip/hip_runtime.h>
#include <cmath>

#define CDIV(a,b) (((a)+(b)-1)/(b))

using u16 = unsigned short;
using short8 = __attribute__((ext_vector_type(8))) short;
using f32x4 = __attribute__((ext_vector_type(4))) float;

__device__ __forceinline__ u16 f2b(float v) {
    union { float f; unsigned u; } x; x.f = v;
    unsigned r = x.u + 0x7fffu + ((x.u >> 16) & 1u);
    return (u16)(r >> 16);
}
__device__ __forceinline__ float b2f(u16 h) {
    union { unsigned u; float f; } x; x.u = ((unsigned)h) << 16;
    return x.f;
}

#if defined(__has_builtin)
#if __has_builtin(__builtin_amdgcn_global_load_lds)
#define HAS_GLL 1
#endif
#endif
#ifndef HAS_GLL
#define HAS_GLL 0
#endif

// async global->LDS, 16B per lane; LDS dest must be linear in lane id.
__device__ __forceinline__ void g2l(const u16* g, uint4* l) {
#if HAS_GLL
    __builtin_amdgcn_global_load_lds((const __attribute__((address_space(1))) void*)g,
                                     (__attribute__((address_space(3))) void*)l, 16, 0, 0);
#else
    *l = *(const uint4*)g;
#endif
}

// ----------------------------- build / norm -----------------------------

__global__ void build_adj_k(const int* __restrict__ ei, float* __restrict__ adj, int E, int ld) {
    int e = blockIdx.x * 256 + threadIdx.x;
    if (e < E) {
        int s = ei[e];
        int d = ei[E + e];
        atomicAdd(&adj[(size_t)s * ld + d], 1.0f);
    }
}

__global__ void rowsum_dinv_b_k(const u16* __restrict__ adjb, int ld, int n, float* __restrict__ dinv) {
    int i = blockIdx.x;
    __shared__ float red[256];
    const u16* row = adjb + (size_t)i * ld;
    float s = 0.f;
    for (int j = threadIdx.x; j < n; j += 256) s += b2f(row[j]);
    red[threadIdx.x] = s; __syncthreads();
    for (int w = 128; w > 0; w >>= 1) {
        if (threadIdx.x < w) red[threadIdx.x] += red[threadIdx.x + w];
        __syncthreads();
    }
    if (threadIdx.x == 0) dinv[i] = rsqrtf(red[0] + 1.0f);
}

// fp32 adj (padded, zero-filled) -> bf16 straight + bf16 transposed
__global__ void conv0_k(const float* __restrict__ in, u16* __restrict__ outS, u16* __restrict__ outT, int n) {
    __shared__ u16 t[64][65];
    int i0 = blockIdx.y * 64, j0 = blockIdx.x * 64;
    for (int e = threadIdx.x; e < 4096; e += 256) {
        int r = e >> 6, c = e & 63;
        u16 v = f2b(in[(size_t)(i0 + r) * n + j0 + c]);
        outS[(size_t)(i0 + r) * n + j0 + c] = v;
        t[r][c] = v;
    }
    __syncthreads();
    for (int e = threadIdx.x; e < 4096; e += 256) {
        int r = e >> 6, c = e & 63;
        outT[(size_t)(j0 + r) * n + i0 + c] = t[c][r];
    }
}

__global__ void transpose_b_k(const u16* __restrict__ in, u16* __restrict__ out, int n) {
    __shared__ u16 t[64][65];
    int i0 = blockIdx.y * 64, j0 = blockIdx.x * 64;
    for (int e = threadIdx.x; e < 4096; e += 256) {
        int r = e >> 6, c = e & 63;
        t[r][c] = in[(size_t)(i0 + r) * n + j0 + c];
    }
    __syncthreads();
    for (int e = threadIdx.x; e < 4096; e += 256) {
        int r = e >> 6, c = e & 63;
        out[(size_t)(j0 + r) * n + i0 + c] = t[c][r];
    }
}

// --------- MFMA GEMM, NT form, padded (no staging guards), gload_lds, BK=64 ---------
// Per K-step: two 128x32 half-tiles. LDS layout within a half (512 x uint4):
//   idx = (R>>4)*64 + kg*16 + (R&15)   (R=row 0..127, kg=K-chunk 0..3)
// Staging slot t (t=tid, tid+256) is linear in thread id (gload_lds requirement);
// fragment reads are 1KB-consecutive per 64-lane wave -> conflict-free.

template<int SA, int SB>
__global__ __launch_bounds__(256) void mm_nt(const u16* __restrict__ A0, const u16* __restrict__ A1,
                                             const u16* __restrict__ B0, const u16* __restrict__ B1,
                                             float* __restrict__ C, const float* __restrict__ cbias,
                                             int M, int N, int lda, int ldb, int ldc,
                                             int kPerZ, int Kpad, size_t cstride) {
    __shared__ uint4 lds_t[(2 + SA + SB) * 1024];
    uint4* Ab  = lds_t;
    uint4* A1b = lds_t + (SA ? 1024 : 0);
    uint4* Bb  = lds_t + (1 + SA) * 1024;
    uint4* B1b = Bb + (SB ? 1024 : 0);

    int tid = threadIdx.x;
    int row0 = blockIdx.y * 128, col0 = blockIdx.x * 128;
    int kbeg = blockIdx.z * kPerZ;
    int kend = min(kbeg + kPerZ, Kpad);
    C += (size_t)blockIdx.z * cstride;

    int wave = tid >> 6, lane = tid & 63;
    int wr = (wave >> 1) * 64, wc = (wave & 1) * 64;
    int lrow = lane & 15, kg = lane >> 4;

    // staging slots
    int tS0 = tid, tS1 = tid + 256;
    int R0 = ((tS0 >> 6) << 4) | (tS0 & 15), kc0 = (tS0 >> 4) & 3;
    int R1 = ((tS1 >> 6) << 4) | (tS1 & 15), kc1 = (tS1 >> 4) & 3;

    const u16* aP0 = A0 + (size_t)(row0 + R0) * lda + kbeg + kc0 * 8;
    const u16* aP1 = A0 + (size_t)(row0 + R1) * lda + kbeg + kc1 * 8;
    const u16* bP0 = B0 + (size_t)(col0 + R0) * ldb + kbeg + kc0 * 8;
    const u16* bP1 = B0 + (size_t)(col0 + R1) * ldb + kbeg + kc1 * 8;
    const u16* a1P0 = SA ? (A1 + (size_t)(row0 + R0) * lda + kbeg + kc0 * 8) : nullptr;
    const u16* a1P1 = SA ? (A1 + (size_t)(row0 + R1) * lda + kbeg + kc1 * 8) : nullptr;
    const u16* b1P0 = SB ? (B1 + (size_t)(col0 + R0) * ldb + kbeg + kc1 * 8 - (kc1 - kc0) * 8) : nullptr;
    const u16* b1P1 = SB ? (B1 + (size_t)(col0 + R1) * ldb + kbeg + kc1 * 8) : nullptr;

    f32x4 acc[4][4] = {};

    int nIter = (kend - kbeg) >> 6;
    for (int it = 0; it < nIter; ++it) {
        __syncthreads();
        g2l(aP0,      Ab + tS0);        g2l(aP0 + 32, Ab + 512 + tS0);
        g2l(aP1,      Ab + tS1);        g2l(aP1 + 32, Ab + 512 + tS1);
        if constexpr (SA) {
            g2l(a1P0,      A1b + tS0);  g2l(a1P0 + 32, A1b + 512 + tS0);
            g2l(a1P1,      A1b + tS1);  g2l(a1P1 + 32, A1b + 512 + tS1);
        }
        g2l(bP0,      Bb + tS0);        g2l(bP0 + 32, Bb + 512 + tS0);
        g2l(bP1,      Bb + tS1);        g2l(bP1 + 32, Bb + 512 + tS1);
        if constexpr (SB) {
            g2l(b1P0,      B1b + tS0);  g2l(b1P0 + 32, B1b + 512 + tS0);
            g2l(b1P1,      B1b + tS1);  g2l(b1P1 + 32, B1b + 512 + tS1);
        }
        __syncthreads();

        const short8* Ap  = (const short8*)Ab;
        const short8* A1p = (const short8*)A1b;
        const short8* Bp  = (const short8*)Bb;
        const short8* B1p = (const short8*)B1b;

#pragma unroll
        for (int ks = 0; ks < 2; ++ks) {
            short8 a[4], a1[4], b[4], b1[4];
#pragma unroll
            for (int m = 0; m < 4; ++m) {
                int idx = ks * 512 + ((((wr >> 4) + m) << 6) | (kg << 4) | lrow);
                a[m] = Ap[idx];
                if constexpr (SA) a1[m] = A1p[idx];
            }
#pragma unroll
            for (int n = 0; n < 4; ++n) {
                int idx = ks * 512 + ((((wc >> 4) + n) << 6) | (kg << 4) | lrow);
                b[n] = Bp[idx];
                if constexpr (SB) b1[n] = B1p[idx];
            }
#pragma unroll
            for (int m = 0; m < 4; ++m)
#pragma unroll
                for (int n = 0; n < 4; ++n) {
                    acc[m][n] = __builtin_amdgcn_mfma_f32_16x16x32_bf16(a[m], b[n], acc[m][n], 0, 0, 0);
                    if constexpr (SA) acc[m][n] = __builtin_amdgcn_mfma_f32_16x16x32_bf16(a1[m], b[n], acc[m][n], 0, 0, 0);
                    if constexpr (SB) acc[m][n] = __builtin_amdgcn_mfma_f32_16x16x32_bf16(a[m], b1[n], acc[m][n], 0, 0, 0);
                }
        }

        aP0 += 64; aP1 += 64; bP0 += 64; bP1 += 64;
        if constexpr (SA) { a1P0 += 64; a1P1 += 64; }
        if constexpr (SB) { b1P0 += 64; b1P1 += 64; }
    }

#pragma unroll
    for (int m = 0; m < 4; ++m) {
        int rm = row0 + wr + m * 16 + kg * 4;
#pragma unroll
        for (int n = 0; n < 4; ++n) {
            int cc = col0 + wc + n * 16 + lrow;
            if (cc >= N) continue;
            float badd = cbias ? cbias[cc] : 0.f;
#pragma unroll
            for (int i = 0; i < 4; ++i) {
                int r = rm + i;
                if (r < M) C[(size_t)r * ldc + cc] = acc[m][n][i] + badd;
            }
        }
    }
}

// ----------------------------- fp32 gemm (small K only) -----------------------------

__global__ __launch_bounds__(256) void gemm64(const float* __restrict__ A, const float* __restrict__ B,
                                              float* __restrict__ C,
                                              int M, int N, int K, int lda, int ldb, int ldc,
                                              const float* __restrict__ bias, int relu) {
    __shared__ float As[16][65];
    __shared__ float Bs[16][65];
    int tid = threadIdx.x;
    int trow = tid / 16, tcol = tid % 16;
    int row0 = blockIdx.y * 64 + trow * 4;
    int col0 = blockIdx.x * 64 + tcol * 4;
    float acc[4][4] = {};
    int am = tid >> 2;
    int ak = (tid & 3) * 4;
    int bk = tid >> 4;
    int bn = (tid & 15) * 4;
    for (int k0 = 0; k0 < K; k0 += 16) {
        int gm = blockIdx.y * 64 + am;
#pragma unroll
        for (int u = 0; u < 4; ++u) {
            int gk = k0 + ak + u;
            As[ak + u][am] = (gm < M && gk < K) ? A[(size_t)gm * lda + gk] : 0.f;
        }
        int gbk = k0 + bk;
#pragma unroll
        for (int u = 0; u < 4; ++u) {
            int gn = blockIdx.x * 64 + bn + u;
            Bs[bk][bn + u] = (gbk < K && gn < N) ? B[(size_t)gbk * ldb + gn] : 0.f;
        }
        __syncthreads();
#pragma unroll
        for (int kk = 0; kk < 16; ++kk) {
            float a[4], b[4];
#pragma unroll
            for (int i = 0; i < 4; ++i) a[i] = As[kk][trow * 4 + i];
#pragma unroll
            for (int j = 0; j < 4; ++j) b[j] = Bs[kk][tcol * 4 + j];
#pragma unroll
            for (int i = 0; i < 4; ++i)
#pragma unroll
                for (int j = 0; j < 4; ++j) acc[i][j] += a[i] * b[j];
        }
        __syncthreads();
    }
#pragma unroll
    for (int i = 0; i < 4; ++i) {
        int r = row0 + i;
        if (r >= M) continue;
#pragma unroll
        for (int j = 0; j < 4; ++j) {
            int c = col0 + j;
            if (c < N) {
                float v = acc[i][j] + (bias ? bias[c] : 0.f);
                if (relu) v = fmaxf(v, 0.f);
                C[(size_t)r * ldc + c] = v;
            }
        }
    }
}

// ----------------------------- GCN glue -----------------------------

// transposing split: zhT/zlT[f][i] = bf16 hi/lo of dinv[i]*xw[i][f]; zero-fill i in [M, ldz)
__global__ void scale_split_k(const float* __restrict__ xw, const float* __restrict__ dinv,
                              u16* __restrict__ zhT, u16* __restrict__ zlT, int M, int ldz) {
    __shared__ float t[32][33];
    int i0 = blockIdx.x * 32, f0 = blockIdx.y * 32;
#pragma unroll
    for (int it = 0; it < 4; ++it) {
        int r = it * 8 + (threadIdx.x >> 5);
        int c = threadIdx.x & 31;
        int i = i0 + r;
        t[r][c] = (i < M) ? dinv[i] * xw[(size_t)i * 128 + f0 + c] : 0.f;
    }
    __syncthreads();
#pragma unroll
    for (int it = 0; it < 4; ++it) {
        int r = it * 8 + (threadIdx.x >> 5);
        int c = threadIdx.x & 31;
        int f = f0 + r, i = i0 + c;
        float v = t[c][r];
        u16 h = f2b(v);
        zhT[(size_t)f * ldz + i] = h;
        zlT[(size_t)f * ldz + i] = f2b(v - b2f(h));
    }
}

__global__ void reduce_gcn_post_k(const float* __restrict__ part, int Z, int Mp,
                                  const float* __restrict__ xw, const float* __restrict__ dinv,
                                  const float* __restrict__ bias, float* __restrict__ y, int relu) {
    int i = blockIdx.x, f = threadIdx.x;
    size_t idx = (size_t)i * 128 + f;
    float s = 0.f;
    for (int z = 0; z < Z; ++z) s += part[(size_t)z * Mp * 128 + idx];
    float di = dinv[i];
    float v = di * s + di * di * xw[idx] + bias[f];
    y[idx] = relu ? fmaxf(v, 0.f) : v;
}

// ----------------------------- pooling -----------------------------

// score with fused ||pw||
__global__ void score_k(const float* __restrict__ x, const float* __restrict__ pw,
                        float* __restrict__ score) {
    int i = blockIdx.x;
    __shared__ float red[128], red2[128];
    float p = pw[threadIdx.x];
    red[threadIdx.x]  = x[(size_t)i * 128 + threadIdx.x] * p;
    red2[threadIdx.x] = p * p;
    __syncthreads();
    for (int s = 64; s > 0; s >>= 1) {
        if (threadIdx.x < s) { red[threadIdx.x] += red[threadIdx.x + s]; red2[threadIdx.x] += red2[threadIdx.x + s]; }
        __syncthreads();
    }
    if (threadIdx.x == 0) score[i] = tanhf(red[0] / sqrtf(red2[0]));
}

// per-slice stable-rank partial counts (no atomics, no memset)
__global__ __launch_bounds__(256) void rank_partial_k(const float* __restrict__ score, int n,
                                                      int* __restrict__ rankpart) {
    __shared__ float s_sh[512];
    int i = blockIdx.x * 256 + threadIdx.x;
    int jbase = blockIdx.y * 512;
    float si = (i < n) ? score[i] : -3.0f;
    for (int t = threadIdx.x; t < 512; t += 256) {
        int j = jbase + t;
        s_sh[t] = (j < n) ? score[j] : -3.0f;
    }
    __syncthreads();
    int cnt = 0;
#pragma unroll 16
    for (int t = 0; t < 512; ++t) {
        float sj = s_sh[t];
        cnt += (sj > si) || (sj == si && (jbase + t) < i);
    }
    if (i < n) rankpart[blockIdx.y * n + i] = cnt;
}

__global__ void scatter_topk_k(const float* __restrict__ score, const int* __restrict__ rankpart,
                               int nsl, int n, int k, int* __restrict__ perm, float* __restrict__ sc) {
    int i = blockIdx.x * 256 + threadIdx.x;
    if (i >= n) return;
    int r = 0;
    for (int s = 0; s < nsl; ++s) r += rankpart[s * n + i];
    if (r < k) { perm[r] = i; sc[r] = score[i]; }
}

__global__ void pool_x_k(float* __restrict__ xo, const float* __restrict__ xi,
                         const int* __restrict__ perm, const float* __restrict__ sc) {
    int a = blockIdx.x, f = threadIdx.x;
    xo[(size_t)a * 128 + f] = xi[(size_t)perm[a] * 128 + f] * sc[a];
}

// two gathers in one dispatch: dst row = src[perm[row], :] with [row][perm[row]] = 1
__global__ void gather2_b_k(const u16* __restrict__ src0, const u16* __restrict__ src1,
                            int ldsrc, const int* __restrict__ perm,
                            u16* __restrict__ dst0, u16* __restrict__ dst1, int width) {
    const u16* src = blockIdx.y ? src1 : src0;
    u16* dst = blockIdx.y ? dst1 : dst0;
    int row = blockIdx.x;
    int p = perm[row];
    const uint4* s4 = (const uint4*)(src + (size_t)p * ldsrc);
    uint4* d4 = (uint4*)(dst + (size_t)row * width);
    int n8 = width >> 3;
    for (int j = threadIdx.x; j < n8; j += 256) d4[j] = s4[j];
    __syncthreads();
    if (threadIdx.x == 0) dst[(size_t)row * width + p] = 0x3F80;  // 1.0 bf16
}

// sum Z slices, zero diag, zero-pad rows/cols >= k (out is [Mp][Mp])
__global__ void reduce_pool_k(const float* __restrict__ part, int Z, int k, int Mp, u16* __restrict__ out) {
    int row = blockIdx.x;
    for (int j = threadIdx.x; j < Mp; j += 256) {
        float s = 0.f;
        if (row < k && j < k) {
            for (int z = 0; z < Z; ++z) s += part[(size_t)z * Mp * Mp + (size_t)row * Mp + j];
            if (j == row) s = 0.f;
        }
        out[(size_t)row * Mp + j] = f2b(s);
    }
}

__global__ void scatter_add_k(float* __restrict__ xdst, const int* __restrict__ perm,
                              const float* __restrict__ xsrc) {
    int a = blockIdx.x, f = threadIdx.x;
    xdst[(size_t)perm[a] * 128 + f] += xsrc[(size_t)a * 128 + f];
}

// ----------------------------- head -----------------------------

__global__ void split_head_k(const float* __restrict__ x, u16* __restrict__ Ah, u16* __restrict__ Al) {
    int i = blockIdx.x, f = threadIdx.x;
    size_t idx = (size_t)i * 128 + f;
    float v = x[idx];
    u16 h = f2b(v);
    Ah[idx] = h;
    Al[idx] = f2b(v - b2f(h));
}

// W3 [128][Nc] fp32 -> W3T [Ncp][128] bf16, rows [Nc,Ncp) zeroed
__global__ void convW3T_k(const float* __restrict__ W3, u16* __restrict__ W3T, int Nc, int Ncp) {
    __shared__ float t[64][65];
    int k0 = blockIdx.y * 64, n0 = blockIdx.x * 64;
    for (int e = threadIdx.x; e < 4096; e += 256) {
        int r = e >> 6, c = e & 63;
        t[r][c] = (k0 + r < 128 && n0 + c < Nc) ? W3[(size_t)(k0 + r) * Nc + n0 + c] : 0.f;
    }
    __syncthreads();
    for (int e = threadIdx.x; e < 4096; e += 256) {
        int r = e >> 6, c = e & 63;
        int nn = n0 + r, kk = k0 + c;
        if (nn < Ncp) W3T[(size_t)nn * 128 + kk] = f2b(t[c][r]);
    }
}

__global__ __launch_bounds__(256) void logsoftmax_k(float* __restrict__ out, int C) {
    int row = blockIdx.x;
    extern __shared__ float buf[];
    __shared__ float red[256];
    float* rowp = out + (size_t)row * C;
    float mx = -1e30f;
    for (int c = threadIdx.x; c < C; c += 256) {
        float v = rowp[c];
        buf[c] = v;
        mx = fmaxf(mx, v);
    }
    red[threadIdx.x] = mx; __syncthreads();
    for (int s = 128; s > 0; s >>= 1) {
        if (threadIdx.x < s) red[threadIdx.x] = fmaxf(red[threadIdx.x], red[threadIdx.x + s]);
        __syncthreads();
    }
    float m = red[0];
    __syncthreads();
    float sum = 0.f;
    for (int c = threadIdx.x; c < C; c += 256) sum += expf(buf[c] - m);
    red[threadIdx.x] = sum; __syncthreads();
    for (int s = 128; s > 0; s >>= 1) {
        if (threadIdx.x < s) red[threadIdx.x] += red[threadIdx.x + s];
        __syncthreads();
    }
    float ls = m + logf(red[0]);
    for (int c = threadIdx.x; c < C; c += 256) rowp[c] = buf[c] - ls;
}

// ----------------------------- entry -----------------------------

extern "C" void kernel_launch(void* const* d_in, const int* in_sizes, int n_in,
                              void* d_out, int out_size, void* d_ws, size_t ws_size,
                              hipStream_t stream) {
    const int N0 = 5000, K1 = 2000, K2 = 1000, K3 = 500, E = 80000, OUTC = 6890;
    const int Np0 = 5120, Kp1 = 2048, Kp2 = 1024, Kp3 = 512, OUTCP = 6912;
    (void)in_sizes; (void)n_in; (void)out_size; (void)ws_size;

    const float* pos = (const float*)d_in[0];
    const int*   ei  = (const int*)d_in[1];
    const float* Wd0 = (const float*)d_in[2];  const float* bd0 = (const float*)d_in[3];
    const float* Wd1 = (const float*)d_in[4];  const float* bd1 = (const float*)d_in[5];
    const float* Wd2 = (const float*)d_in[6];  const float* bd2 = (const float*)d_in[7];
    const float* Wd3 = (const float*)d_in[8];  const float* bd3 = (const float*)d_in[9];
    const float* pw0 = (const float*)d_in[10];
    const float* pw1 = (const float*)d_in[11];
    const float* pw2 = (const float*)d_in[12];
    const float* Wu0 = (const float*)d_in[13]; const float* bu0 = (const float*)d_in[14];
    const float* Wu1 = (const float*)d_in[15]; const float* bu1 = (const float*)d_in[16];
    const float* Wu2 = (const float*)d_in[17]; const float* bu2 = (const float*)d_in[18];
    const float* W1  = (const float*)d_in[19]; const float* b1  = (const float*)d_in[20];
    const float* W2  = (const float*)d_in[21]; const float* b2  = (const float*)d_in[22];
    const float* W3  = (const float*)d_in[23]; const float* b3  = (const float*)d_in[24];

    float* w = (float*)d_ws;
    size_t off = 0;
    auto alloc = [&](size_t nel) { float* p = w + off; off += nel; return p; };

    // pool region (26.22M floats = 5120^2): adj0 fp32 transiently; then
    //   partials [0,13M) | G [13M,18.25M) | HT [18.25M,23.5M)
    //   zhT/zlT overlap G (GCN phase only); Ah/Al overlap partials (head phase only)
    float* pool = alloc(26220000);
    float* adj0 = pool;
    float* partials = pool;
    u16* G   = (u16*)(pool + 13000000);
    u16* HT  = (u16*)(pool + 18250000);
    u16* zhT = (u16*)(pool + 13000000);
    u16* zlT = (u16*)(pool + 13400000);
    u16* Ah  = (u16*)(pool);
    u16* Al  = (u16*)(pool + 400000);

    u16* adj0b  = (u16*)alloc(13107200);     // 5120 x 5120
    u16* adj0bT = (u16*)alloc(13107200);
    u16* adj1b  = (u16*)alloc(2097152);      // 2048 x 2048
    u16* adj1bT = (u16*)alloc(2097152);
    u16* adj2b  = (u16*)alloc(524288);       // 1024 x 1024
    u16* adj2bT = (u16*)alloc(524288);
    u16* adj3b  = (u16*)alloc(131072);       // 512 x 512
    u16* W3T    = (u16*)alloc(442368);       // 6912 x 128

    float* x0 = alloc((size_t)N0 * 128);
    float* x1 = alloc((size_t)K1 * 128);
    float* x2 = alloc((size_t)K2 * 128);
    float* xa = alloc((size_t)N0 * 128);
    float* xb = alloc((size_t)N0 * 128);
    float* xw = alloc((size_t)N0 * 128);
    float* dinv0 = alloc(N0); float* dinv1 = alloc(K1); float* dinv2 = alloc(K2); float* dinv3 = alloc(K3);
    float* scorev = alloc(N0);
    float* scv    = alloc(K1);
    int* perm0 = (int*)alloc(K1);
    int* perm1 = (int*)alloc(K2);
    int* perm2 = (int*)alloc(K3);
    int* rankpart = (int*)alloc(50048);      // up to 10 slices x 5000

    auto launch_mm = [&](int SA, int SB, const u16* A0, const u16* A1, const u16* B0, const u16* B1,
                         float* Cc, const float* cbias, int M, int N, int Kpad,
                         int lda, int ldb, int ldc, size_t cstride, int Z) -> int {
        int kPerZ = CDIV(Kpad, Z * 64) * 64;
        int gz = CDIV(Kpad, kPerZ);
        dim3 g(CDIV(N, 128), CDIV(M, 128), gz);
        if (SA)      mm_nt<1, 0><<<g, 256, 0, stream>>>(A0, A1, B0, B1, Cc, cbias, M, N, lda, ldb, ldc, kPerZ, Kpad, cstride);
        else if (SB) mm_nt<0, 1><<<g, 256, 0, stream>>>(A0, A1, B0, B1, Cc, cbias, M, N, lda, ldb, ldc, kPerZ, Kpad, cstride);
        else         mm_nt<0, 0><<<g, 256, 0, stream>>>(A0, A1, B0, B1, Cc, cbias, M, N, lda, ldb, ldc, kPerZ, Kpad, cstride);
        return gz;
    };

    // gcn: y = act(dinv*(adjb @ (dinv*x@W)) + dinv^2*(x@W) + b), adjb padded [Mp][Np=Mp]
    auto run_gcn = [&](const u16* adjb, int n, int Np,
                       const float* x, int kin, const float* W, const float* bias,
                       const float* dinv, int relu, float* y, int Z) {
        gemm64<<<dim3(2, CDIV(n, 64)), 256, 0, stream>>>(x, W, xw, n, 128, kin, kin, 128, 128, nullptr, 0);
        scale_split_k<<<dim3(Np / 32, 4), 256, 0, stream>>>(xw, dinv, zhT, zlT, n, Np);
        int gz = launch_mm(0, 1, adjb, nullptr, zhT, zlT, partials, nullptr,
                           Np, 128, Np, Np, Np, 128, (size_t)Np * 128, Z);
        reduce_gcn_post_k<<<n, 128, 0, stream>>>(partials, gz, Np, xw, dinv, bias, y, relu);
    };

    auto run_pool = [&](const float* x, int n, int Np, int kNew, int KpNew, const float* pw,
                        const u16* srcb, const u16* srcbT, u16* adjNew, int* perm, int Z) {
        score_k<<<n, 128, 0, stream>>>(x, pw, scorev);
        int nsl = CDIV(n, 512);
        rank_partial_k<<<dim3(CDIV(n, 256), nsl), 256, 0, stream>>>(scorev, n, rankpart);
        scatter_topk_k<<<CDIV(n, 256), 256, 0, stream>>>(scorev, rankpart, nsl, n, kNew, perm, scv);
        pool_x_k<<<kNew, 128, 0, stream>>>(xa, x, perm, scv);
        gather2_b_k<<<dim3(kNew, 2), 256, 0, stream>>>(srcb, srcbT, Np, perm, G, HT, Np);
        int gz = launch_mm(0, 0, G, nullptr, HT, nullptr, partials, nullptr,
                           KpNew, KpNew, Np, Np, Np, KpNew, (size_t)KpNew * KpNew, Z);
        reduce_pool_k<<<KpNew, 256, 0, stream>>>(partials, gz, kNew, KpNew, adjNew);
    };

    // ---- build adjacency (padded fp32), convert to bf16 + bf16^T, dinv0 ----
    hipMemsetAsync(adj0, 0, (size_t)Np0 * Np0 * sizeof(float), stream);
    build_adj_k<<<CDIV(E, 256), 256, 0, stream>>>(ei, adj0, E, Np0);
    conv0_k<<<dim3(Np0 / 64, Np0 / 64), 256, 0, stream>>>(adj0, adj0b, adj0bT, Np0);
    rowsum_dinv_b_k<<<N0, 256, 0, stream>>>(adj0b, Np0, Np0, dinv0);

    // ---- initial GCN ----
    run_gcn(adj0b, N0, Np0, pos, 3, Wd0, bd0, dinv0, 1, x0, 10);

    // ---- down level 0: 5000 -> 2000 ----
    run_pool(x0, N0, Np0, K1, Kp1, pw0, adj0b, adj0bT, adj1b, perm0, 3);
    transpose_b_k<<<dim3(Kp1 / 64, Kp1 / 64), 256, 0, stream>>>(adj1b, adj1bT, Kp1);
    rowsum_dinv_b_k<<<K1, 256, 0, stream>>>(adj1b, Kp1, Kp1, dinv1);
    run_gcn(adj1b, K1, Kp1, xa, 128, Wd1, bd1, dinv1, 1, x1, 16);

    // ---- down level 1: 2000 -> 1000 ----
    run_pool(x1, K1, Kp1, K2, Kp2, pw1, adj1b, adj1bT, adj2b, perm1, 8);
    transpose_b_k<<<dim3(Kp2 / 64, Kp2 / 64), 256, 0, stream>>>(adj2b, adj2bT, Kp2);
    rowsum_dinv_b_k<<<K2, 256, 0, stream>>>(adj2b, Kp2, Kp2, dinv2);
    run_gcn(adj2b, K2, Kp2, xa, 128, Wd2, bd2, dinv2, 1, x2, 16);

    // ---- down level 2: 1000 -> 500 ----
    run_pool(x2, K2, Kp2, K3, Kp3, pw2, adj2b, adj2bT, adj3b, perm2, 8);
    rowsum_dinv_b_k<<<K3, 256, 0, stream>>>(adj3b, Kp3, Kp3, dinv3);
    run_gcn(adj3b, K3, Kp3, xa, 128, Wd3, bd3, dinv3, 1, xb, 8);           // xb: 500x128

    // ---- up i=0 (j=2) ----
    hipMemcpyAsync(xa, x2, (size_t)K2 * 128 * sizeof(float), hipMemcpyDeviceToDevice, stream);
    scatter_add_k<<<K3, 128, 0, stream>>>(xa, perm2, xb);
    run_gcn(adj2b, K2, Kp2, xa, 128, Wu0, bu0, dinv2, 1, xb, 16);          // xb: 1000x128

    // ---- up i=1 (j=1) ----
    hipMemcpyAsync(xa, x1, (size_t)K1 * 128 * sizeof(float), hipMemcpyDeviceToDevice, stream);
    scatter_add_k<<<K2, 128, 0, stream>>>(xa, perm1, xb);
    run_gcn(adj1b, K1, Kp1, xa, 128, Wu1, bu1, dinv1, 1, xb, 16);          // xb: 2000x128

    // ---- up i=2 (j=0), no relu ----
    hipMemcpyAsync(xa, x0, (size_t)N0 * 128 * sizeof(float), hipMemcpyDeviceToDevice, stream);
    scatter_add_k<<<K1, 128, 0, stream>>>(xa, perm0, xb);
    run_gcn(adj0b, N0, Np0, xa, 128, Wu2, bu2, dinv0, 0, xb, 10);          // xb: 5000x128

    // ---- MLP head (bias+relu fused in gemm64 epilogue) ----
    gemm64<<<dim3(2, CDIV(N0, 64)), 256, 0, stream>>>(xb, W1, xa, N0, 128, 128, 128, 128, 128, b1, 1);
    gemm64<<<dim3(2, CDIV(N0, 64)), 256, 0, stream>>>(xa, W2, xw, N0, 128, 128, 128, 128, 128, b2, 0);

    split_head_k<<<N0, 128, 0, stream>>>(xw, Ah, Al);
    convW3T_k<<<dim3(OUTCP / 64, 2), 256, 0, stream>>>(W3, W3T, OUTC, OUTCP);

    float* outp = (float*)d_out;
    launch_mm(1, 0, Ah, Al, W3T, nullptr, outp, b3, N0, OUTC, 128, 128, 128, OUTC, 0, 1);
    logsoftmax_k<<<N0, 256, OUTC * sizeof(float), stream>>>(outp, OUTC);
}

// Round 9
// 923.547 us; speedup vs baseline: 1.0099x; 1.0099x over previous
//
#include <hip/hip_runtime.h>
#include <cmath>

#define CDIV(a,b) (((a)+(b)-1)/(b))

using u16 = unsigned short;
using short8 = __attribute__((ext_vector_type(8))) short;
using f32x4 = __attribute__((ext_vector_type(4))) float;

__device__ __forceinline__ u16 f2b(float v) {
    union { float f; unsigned u; } x; x.f = v;
    unsigned r = x.u + 0x7fffu + ((x.u >> 16) & 1u);
    return (u16)(r >> 16);
}
__device__ __forceinline__ float b2f(u16 h) {
    union { unsigned u; float f; } x; x.u = ((unsigned)h) << 16;
    return x.f;
}

#if defined(__has_builtin)
#if __has_builtin(__builtin_amdgcn_global_load_lds)
#define HAS_GLL 1
#endif
#endif
#ifndef HAS_GLL
#define HAS_GLL 0
#endif

// async global->LDS, 16B per lane; LDS dest must be linear in lane id.
__device__ __forceinline__ void g2l(const u16* g, uint4* l) {
#if HAS_GLL
    __builtin_amdgcn_global_load_lds((const __attribute__((address_space(1))) void*)g,
                                     (__attribute__((address_space(3))) void*)l, 16, 0, 0);
#else
    *l = *(const uint4*)g;
#endif
}

// ----------------------------- build / norm -----------------------------

__global__ void build_adj_k(const int* __restrict__ ei, float* __restrict__ adj, int E, int ld) {
    int e = blockIdx.x * 256 + threadIdx.x;
    if (e < E) {
        int s = ei[e];
        int d = ei[E + e];
        atomicAdd(&adj[(size_t)s * ld + d], 1.0f);
    }
}

__global__ void rowsum_dinv_b_k(const u16* __restrict__ adjb, int ld, int n, float* __restrict__ dinv) {
    int i = blockIdx.x;
    __shared__ float red[256];
    const u16* row = adjb + (size_t)i * ld;
    float s = 0.f;
    for (int j = threadIdx.x; j < n; j += 256) s += b2f(row[j]);
    red[threadIdx.x] = s; __syncthreads();
    for (int w = 128; w > 0; w >>= 1) {
        if (threadIdx.x < w) red[threadIdx.x] += red[threadIdx.x + w];
        __syncthreads();
    }
    if (threadIdx.x == 0) dinv[i] = rsqrtf(red[0] + 1.0f);
}

// fp32 adj (padded, zero-filled) -> bf16 straight + bf16 transposed
__global__ void conv0_k(const float* __restrict__ in, u16* __restrict__ outS, u16* __restrict__ outT, int n) {
    __shared__ u16 t[64][65];
    int i0 = blockIdx.y * 64, j0 = blockIdx.x * 64;
    for (int e = threadIdx.x; e < 4096; e += 256) {
        int r = e >> 6, c = e & 63;
        u16 v = f2b(in[(size_t)(i0 + r) * n + j0 + c]);
        outS[(size_t)(i0 + r) * n + j0 + c] = v;
        t[r][c] = v;
    }
    __syncthreads();
    for (int e = threadIdx.x; e < 4096; e += 256) {
        int r = e >> 6, c = e & 63;
        outT[(size_t)(j0 + r) * n + i0 + c] = t[c][r];
    }
}

__global__ void transpose_b_k(const u16* __restrict__ in, u16* __restrict__ out, int n) {
    __shared__ u16 t[64][65];
    int i0 = blockIdx.y * 64, j0 = blockIdx.x * 64;
    for (int e = threadIdx.x; e < 4096; e += 256) {
        int r = e >> 6, c = e & 63;
        t[r][c] = in[(size_t)(i0 + r) * n + j0 + c];
    }
    __syncthreads();
    for (int e = threadIdx.x; e < 4096; e += 256) {
        int r = e >> 6, c = e & 63;
        out[(size_t)(j0 + r) * n + i0 + c] = t[c][r];
    }
}

// --------- MFMA GEMM, NT form, padded (no staging guards), gload_lds, BK=32 ---------
// LDS layout (512 x uint4 per matrix): idx = (R>>4)*64 + kg*16 + (R&15)
//   (R = tile row 0..127, kg = K-chunk 0..3).
// Staging slot == thread id (linear, required by global_load_lds); fragment reads are
// 1KB-consecutive per 64-lane wave -> conflict-free. Global pointers hoisted, += 32/iter.
// XCD-aware chunked swizzle on the x-y plane when (gx*gy)%8==0 (bijective).

template<int SA, int SB>
__global__ __launch_bounds__(256) void mm_nt(const u16* __restrict__ A0, const u16* __restrict__ A1,
                                             const u16* __restrict__ B0, const u16* __restrict__ B1,
                                             float* __restrict__ C, const float* __restrict__ cbias,
                                             int M, int N, int lda, int ldb, int ldc,
                                             int kPerZ, int Kpad, size_t cstride) {
    __shared__ uint4 lds_t[(2 + SA + SB) * 512];
    uint4* Ab  = lds_t;
    uint4* A1b = lds_t + (SA ? 512 : 0);
    uint4* Bb  = lds_t + (1 + SA) * 512;
    uint4* B1b = Bb + (SB ? 512 : 0);

    int tid = threadIdx.x;

    // XCD-aware swizzle of the x-y plane (identity when plane not 8-divisible)
    int nx = gridDim.x, nxy = nx * gridDim.y;
    int bx = blockIdx.x, by = blockIdx.y;
    if ((nxy & 7) == 0) {
        int flat = by * nx + bx;
        int nf = (flat & 7) * (nxy >> 3) + (flat >> 3);
        bx = nf % nx; by = nf / nx;
    }
    int row0 = by * 128, col0 = bx * 128;

    int kbeg = blockIdx.z * kPerZ;
    int kend = min(kbeg + kPerZ, Kpad);
    C += (size_t)blockIdx.z * cstride;

    int wave = tid >> 6, lane = tid & 63;
    int wr = (wave >> 1) * 64, wc = (wave & 1) * 64;
    int lrow = lane & 15, kg = lane >> 4;

    // staging slots (two per thread)
    int tS0 = tid, tS1 = tid + 256;
    int R0 = ((tS0 >> 6) << 4) | (tS0 & 15), kc0 = (tS0 >> 4) & 3;
    int R1 = ((tS1 >> 6) << 4) | (tS1 & 15), kc1 = (tS1 >> 4) & 3;

    const u16* aP0 = A0 + (size_t)(row0 + R0) * lda + kbeg + kc0 * 8;
    const u16* aP1 = A0 + (size_t)(row0 + R1) * lda + kbeg + kc1 * 8;
    const u16* bP0 = B0 + (size_t)(col0 + R0) * ldb + kbeg + kc0 * 8;
    const u16* bP1 = B0 + (size_t)(col0 + R1) * ldb + kbeg + kc1 * 8;
    const u16* a1P0 = SA ? (A1 + (size_t)(row0 + R0) * lda + kbeg + kc0 * 8) : nullptr;
    const u16* a1P1 = SA ? (A1 + (size_t)(row0 + R1) * lda + kbeg + kc1 * 8) : nullptr;
    const u16* b1P0 = SB ? (B1 + (size_t)(col0 + R0) * ldb + kbeg + kc0 * 8) : nullptr;
    const u16* b1P1 = SB ? (B1 + (size_t)(col0 + R1) * ldb + kbeg + kc1 * 8) : nullptr;

    f32x4 acc[4][4] = {};

    for (int k0 = kbeg; k0 < kend; k0 += 32) {
        __syncthreads();
        g2l(aP0, Ab + tS0);
        g2l(aP1, Ab + tS1);
        if constexpr (SA) { g2l(a1P0, A1b + tS0); g2l(a1P1, A1b + tS1); }
        g2l(bP0, Bb + tS0);
        g2l(bP1, Bb + tS1);
        if constexpr (SB) { g2l(b1P0, B1b + tS0); g2l(b1P1, B1b + tS1); }
        __syncthreads();

        const short8* Ap  = (const short8*)Ab;
        const short8* A1p = (const short8*)A1b;
        const short8* Bp  = (const short8*)Bb;
        const short8* B1p = (const short8*)B1b;

        short8 a[4], a1[4], b[4], b1[4];
#pragma unroll
        for (int m = 0; m < 4; ++m) {
            int idx = (((wr >> 4) + m) << 6) | (kg << 4) | lrow;
            a[m] = Ap[idx];
            if constexpr (SA) a1[m] = A1p[idx];
        }
#pragma unroll
        for (int n = 0; n < 4; ++n) {
            int idx = (((wc >> 4) + n) << 6) | (kg << 4) | lrow;
            b[n] = Bp[idx];
            if constexpr (SB) b1[n] = B1p[idx];
        }
#pragma unroll
        for (int m = 0; m < 4; ++m)
#pragma unroll
            for (int n = 0; n < 4; ++n) {
                acc[m][n] = __builtin_amdgcn_mfma_f32_16x16x32_bf16(a[m], b[n], acc[m][n], 0, 0, 0);
                if constexpr (SA) acc[m][n] = __builtin_amdgcn_mfma_f32_16x16x32_bf16(a1[m], b[n], acc[m][n], 0, 0, 0);
                if constexpr (SB) acc[m][n] = __builtin_amdgcn_mfma_f32_16x16x32_bf16(a[m], b1[n], acc[m][n], 0, 0, 0);
            }

        aP0 += 32; aP1 += 32; bP0 += 32; bP1 += 32;
        if constexpr (SA) { a1P0 += 32; a1P1 += 32; }
        if constexpr (SB) { b1P0 += 32; b1P1 += 32; }
    }

#pragma unroll
    for (int m = 0; m < 4; ++m) {
        int rm = row0 + wr + m * 16 + kg * 4;
#pragma unroll
        for (int n = 0; n < 4; ++n) {
            int cc = col0 + wc + n * 16 + lrow;
            if (cc >= N) continue;
            float badd = cbias ? cbias[cc] : 0.f;
#pragma unroll
            for (int i = 0; i < 4; ++i) {
                int r = rm + i;
                if (r < M) C[(size_t)r * ldc + cc] = acc[m][n][i] + badd;
            }
        }
    }
}

// ----------------------------- fp32 gemm (small K only) -----------------------------

__global__ __launch_bounds__(256) void gemm64(const float* __restrict__ A, const float* __restrict__ B,
                                              float* __restrict__ C,
                                              int M, int N, int K, int lda, int ldb, int ldc,
                                              const float* __restrict__ bias, int relu) {
    __shared__ float As[16][65];
    __shared__ float Bs[16][65];
    int tid = threadIdx.x;
    int trow = tid / 16, tcol = tid % 16;
    int row0 = blockIdx.y * 64 + trow * 4;
    int col0 = blockIdx.x * 64 + tcol * 4;
    float acc[4][4] = {};
    int am = tid >> 2;
    int ak = (tid & 3) * 4;
    int bk = tid >> 4;
    int bn = (tid & 15) * 4;
    for (int k0 = 0; k0 < K; k0 += 16) {
        int gm = blockIdx.y * 64 + am;
#pragma unroll
        for (int u = 0; u < 4; ++u) {
            int gk = k0 + ak + u;
            As[ak + u][am] = (gm < M && gk < K) ? A[(size_t)gm * lda + gk] : 0.f;
        }
        int gbk = k0 + bk;
#pragma unroll
        for (int u = 0; u < 4; ++u) {
            int gn = blockIdx.x * 64 + bn + u;
            Bs[bk][bn + u] = (gbk < K && gn < N) ? B[(size_t)gbk * ldb + gn] : 0.f;
        }
        __syncthreads();
#pragma unroll
        for (int kk = 0; kk < 16; ++kk) {
            float a[4], b[4];
#pragma unroll
            for (int i = 0; i < 4; ++i) a[i] = As[kk][trow * 4 + i];
#pragma unroll
            for (int j = 0; j < 4; ++j) b[j] = Bs[kk][tcol * 4 + j];
#pragma unroll
            for (int i = 0; i < 4; ++i)
#pragma unroll
                for (int j = 0; j < 4; ++j) acc[i][j] += a[i] * b[j];
        }
        __syncthreads();
    }
#pragma unroll
    for (int i = 0; i < 4; ++i) {
        int r = row0 + i;
        if (r >= M) continue;
#pragma unroll
        for (int j = 0; j < 4; ++j) {
            int c = col0 + j;
            if (c < N) {
                float v = acc[i][j] + (bias ? bias[c] : 0.f);
                if (relu) v = fmaxf(v, 0.f);
                C[(size_t)r * ldc + c] = v;
            }
        }
    }
}

// ----------------------------- GCN glue -----------------------------

// transposing split: zhT/zlT[f][i] = bf16 hi/lo of dinv[i]*xw[i][f]; zero-fill i in [M, ldz)
__global__ void scale_split_k(const float* __restrict__ xw, const float* __restrict__ dinv,
                              u16* __restrict__ zhT, u16* __restrict__ zlT, int M, int ldz) {
    __shared__ float t[32][33];
    int i0 = blockIdx.x * 32, f0 = blockIdx.y * 32;
#pragma unroll
    for (int it = 0; it < 4; ++it) {
        int r = it * 8 + (threadIdx.x >> 5);
        int c = threadIdx.x & 31;
        int i = i0 + r;
        t[r][c] = (i < M) ? dinv[i] * xw[(size_t)i * 128 + f0 + c] : 0.f;
    }
    __syncthreads();
#pragma unroll
    for (int it = 0; it < 4; ++it) {
        int r = it * 8 + (threadIdx.x >> 5);
        int c = threadIdx.x & 31;
        int f = f0 + r, i = i0 + c;
        float v = t[c][r];
        u16 h = f2b(v);
        zhT[(size_t)f * ldz + i] = h;
        zlT[(size_t)f * ldz + i] = f2b(v - b2f(h));
    }
}

__global__ void reduce_gcn_post_k(const float* __restrict__ part, int Z, int Mp,
                                  const float* __restrict__ xw, const float* __restrict__ dinv,
                                  const float* __restrict__ bias, float* __restrict__ y, int relu) {
    int i = blockIdx.x, f = threadIdx.x;
    size_t idx = (size_t)i * 128 + f;
    float s = 0.f;
    for (int z = 0; z < Z; ++z) s += part[(size_t)z * Mp * 128 + idx];
    float di = dinv[i];
    float v = di * s + di * di * xw[idx] + bias[f];
    y[idx] = relu ? fmaxf(v, 0.f) : v;
}

// ----------------------------- pooling -----------------------------

// score with fused ||pw||
__global__ void score_k(const float* __restrict__ x, const float* __restrict__ pw,
                        float* __restrict__ score) {
    int i = blockIdx.x;
    __shared__ float red[128], red2[128];
    float p = pw[threadIdx.x];
    red[threadIdx.x]  = x[(size_t)i * 128 + threadIdx.x] * p;
    red2[threadIdx.x] = p * p;
    __syncthreads();
    for (int s = 64; s > 0; s >>= 1) {
        if (threadIdx.x < s) { red[threadIdx.x] += red[threadIdx.x + s]; red2[threadIdx.x] += red2[threadIdx.x + s]; }
        __syncthreads();
    }
    if (threadIdx.x == 0) score[i] = tanhf(red[0] / sqrtf(red2[0]));
}

// per-slice stable-rank partial counts (no atomics, no memset)
__global__ __launch_bounds__(256) void rank_partial_k(const float* __restrict__ score, int n,
                                                      int* __restrict__ rankpart) {
    __shared__ float s_sh[512];
    int i = blockIdx.x * 256 + threadIdx.x;
    int jbase = blockIdx.y * 512;
    float si = (i < n) ? score[i] : -3.0f;
    for (int t = threadIdx.x; t < 512; t += 256) {
        int j = jbase + t;
        s_sh[t] = (j < n) ? score[j] : -3.0f;
    }
    __syncthreads();
    int cnt = 0;
#pragma unroll 16
    for (int t = 0; t < 512; ++t) {
        float sj = s_sh[t];
        cnt += (sj > si) || (sj == si && (jbase + t) < i);
    }
    if (i < n) rankpart[blockIdx.y * n + i] = cnt;
}

__global__ void scatter_topk_k(const float* __restrict__ score, const int* __restrict__ rankpart,
                               int nsl, int n, int k, int* __restrict__ perm, float* __restrict__ sc) {
    int i = blockIdx.x * 256 + threadIdx.x;
    if (i >= n) return;
    int r = 0;
    for (int s = 0; s < nsl; ++s) r += rankpart[s * n + i];
    if (r < k) { perm[r] = i; sc[r] = score[i]; }
}

__global__ void pool_x_k(float* __restrict__ xo, const float* __restrict__ xi,
                         const int* __restrict__ perm, const float* __restrict__ sc) {
    int a = blockIdx.x, f = threadIdx.x;
    xo[(size_t)a * 128 + f] = xi[(size_t)perm[a] * 128 + f] * sc[a];
}

// two gathers in one dispatch: dst row = src[perm[row], :] with [row][perm[row]] = 1
__global__ void gather2_b_k(const u16* __restrict__ src0, const u16* __restrict__ src1,
                            int ldsrc, const int* __restrict__ perm,
                            u16* __restrict__ dst0, u16* __restrict__ dst1, int width) {
    const u16* src = blockIdx.y ? src1 : src0;
    u16* dst = blockIdx.y ? dst1 : dst0;
    int row = blockIdx.x;
    int p = perm[row];
    const uint4* s4 = (const uint4*)(src + (size_t)p * ldsrc);
    uint4* d4 = (uint4*)(dst + (size_t)row * width);
    int n8 = width >> 3;
    for (int j = threadIdx.x; j < n8; j += 256) d4[j] = s4[j];
    __syncthreads();
    if (threadIdx.x == 0) dst[(size_t)row * width + p] = 0x3F80;  // 1.0 bf16
}

// sum Z slices, zero diag, zero-pad rows/cols >= k (out is [Mp][Mp])
__global__ void reduce_pool_k(const float* __restrict__ part, int Z, int k, int Mp, u16* __restrict__ out) {
    int row = blockIdx.x;
    for (int j = threadIdx.x; j < Mp; j += 256) {
        float s = 0.f;
        if (row < k && j < k) {
            for (int z = 0; z < Z; ++z) s += part[(size_t)z * Mp * Mp + (size_t)row * Mp + j];
            if (j == row) s = 0.f;
        }
        out[(size_t)row * Mp + j] = f2b(s);
    }
}

__global__ void scatter_add_k(float* __restrict__ xdst, const int* __restrict__ perm,
                              const float* __restrict__ xsrc) {
    int a = blockIdx.x, f = threadIdx.x;
    xdst[(size_t)perm[a] * 128 + f] += xsrc[(size_t)a * 128 + f];
}

// ----------------------------- head -----------------------------

__global__ void split_head_k(const float* __restrict__ x, u16* __restrict__ Ah, u16* __restrict__ Al) {
    int i = blockIdx.x, f = threadIdx.x;
    size_t idx = (size_t)i * 128 + f;
    float v = x[idx];
    u16 h = f2b(v);
    Ah[idx] = h;
    Al[idx] = f2b(v - b2f(h));
}

// W3 [128][Nc] fp32 -> W3T [Ncp][128] bf16, rows [Nc,Ncp) zeroed
__global__ void convW3T_k(const float* __restrict__ W3, u16* __restrict__ W3T, int Nc, int Ncp) {
    __shared__ float t[64][65];
    int k0 = blockIdx.y * 64, n0 = blockIdx.x * 64;
    for (int e = threadIdx.x; e < 4096; e += 256) {
        int r = e >> 6, c = e & 63;
        t[r][c] = (k0 + r < 128 && n0 + c < Nc) ? W3[(size_t)(k0 + r) * Nc + n0 + c] : 0.f;
    }
    __syncthreads();
    for (int e = threadIdx.x; e < 4096; e += 256) {
        int r = e >> 6, c = e & 63;
        int nn = n0 + r, kk = k0 + c;
        if (nn < Ncp) W3T[(size_t)nn * 128 + kk] = f2b(t[c][r]);
    }
}

__global__ __launch_bounds__(256) void logsoftmax_k(float* __restrict__ out, int C) {
    int row = blockIdx.x;
    extern __shared__ float buf[];
    __shared__ float red[256];
    float* rowp = out + (size_t)row * C;
    float mx = -1e30f;
    for (int c = threadIdx.x; c < C; c += 256) {
        float v = rowp[c];
        buf[c] = v;
        mx = fmaxf(mx, v);
    }
    red[threadIdx.x] = mx; __syncthreads();
    for (int s = 128; s > 0; s >>= 1) {
        if (threadIdx.x < s) red[threadIdx.x] = fmaxf(red[threadIdx.x], red[threadIdx.x + s]);
        __syncthreads();
    }
    float m = red[0];
    __syncthreads();
    float sum = 0.f;
    for (int c = threadIdx.x; c < C; c += 256) sum += expf(buf[c] - m);
    red[threadIdx.x] = sum; __syncthreads();
    for (int s = 128; s > 0; s >>= 1) {
        if (threadIdx.x < s) red[threadIdx.x] += red[threadIdx.x + s];
        __syncthreads();
    }
    float ls = m + logf(red[0]);
    for (int c = threadIdx.x; c < C; c += 256) rowp[c] = buf[c] - ls;
}

// ----------------------------- entry -----------------------------

extern "C" void kernel_launch(void* const* d_in, const int* in_sizes, int n_in,
                              void* d_out, int out_size, void* d_ws, size_t ws_size,
                              hipStream_t stream) {
    const int N0 = 5000, K1 = 2000, K2 = 1000, K3 = 500, E = 80000, OUTC = 6890;
    const int Np0 = 5120, Kp1 = 2048, Kp2 = 1024, Kp3 = 512, OUTCP = 6912;
    (void)in_sizes; (void)n_in; (void)out_size; (void)ws_size;

    const float* pos = (const float*)d_in[0];
    const int*   ei  = (const int*)d_in[1];
    const float* Wd0 = (const float*)d_in[2];  const float* bd0 = (const float*)d_in[3];
    const float* Wd1 = (const float*)d_in[4];  const float* bd1 = (const float*)d_in[5];
    const float* Wd2 = (const float*)d_in[6];  const float* bd2 = (const float*)d_in[7];
    const float* Wd3 = (const float*)d_in[8];  const float* bd3 = (const float*)d_in[9];
    const float* pw0 = (const float*)d_in[10];
    const float* pw1 = (const float*)d_in[11];
    const float* pw2 = (const float*)d_in[12];
    const float* Wu0 = (const float*)d_in[13]; const float* bu0 = (const float*)d_in[14];
    const float* Wu1 = (const float*)d_in[15]; const float* bu1 = (const float*)d_in[16];
    const float* Wu2 = (const float*)d_in[17]; const float* bu2 = (const float*)d_in[18];
    const float* W1  = (const float*)d_in[19]; const float* b1  = (const float*)d_in[20];
    const float* W2  = (const float*)d_in[21]; const float* b2  = (const float*)d_in[22];
    const float* W3  = (const float*)d_in[23]; const float* b3  = (const float*)d_in[24];

    float* w = (float*)d_ws;
    size_t off = 0;
    auto alloc = [&](size_t nel) { float* p = w + off; off += nel; return p; };

    // pool region (26.22M floats = 5120^2): adj0 fp32 transiently; then
    //   partials [0,13M) | G [13M,18.25M) | HT [18.25M,23.5M)
    //   zhT/zlT overlap G (GCN phase only); Ah/Al overlap partials (head phase only)
    float* pool = alloc(26220000);
    float* adj0 = pool;
    float* partials = pool;
    u16* G   = (u16*)(pool + 13000000);
    u16* HT  = (u16*)(pool + 18250000);
    u16* zhT = (u16*)(pool + 13000000);
    u16* zlT = (u16*)(pool + 13400000);
    u16* Ah  = (u16*)(pool);
    u16* Al  = (u16*)(pool + 400000);

    u16* adj0b  = (u16*)alloc(13107200);     // 5120 x 5120
    u16* adj0bT = (u16*)alloc(13107200);
    u16* adj1b  = (u16*)alloc(2097152);      // 2048 x 2048
    u16* adj1bT = (u16*)alloc(2097152);
    u16* adj2b  = (u16*)alloc(524288);       // 1024 x 1024
    u16* adj2bT = (u16*)alloc(524288);
    u16* adj3b  = (u16*)alloc(131072);       // 512 x 512
    u16* W3T    = (u16*)alloc(442368);       // 6912 x 128

    float* x0 = alloc((size_t)N0 * 128);
    float* x1 = alloc((size_t)K1 * 128);
    float* x2 = alloc((size_t)K2 * 128);
    float* xa = alloc((size_t)N0 * 128);
    float* xb = alloc((size_t)N0 * 128);
    float* xw = alloc((size_t)N0 * 128);
    float* dinv0 = alloc(N0); float* dinv1 = alloc(K1); float* dinv2 = alloc(K2); float* dinv3 = alloc(K3);
    float* scorev = alloc(N0);
    float* scv    = alloc(K1);
    int* perm0 = (int*)alloc(K1);
    int* perm1 = (int*)alloc(K2);
    int* perm2 = (int*)alloc(K3);
    int* rankpart = (int*)alloc(50048);      // up to 10 slices x 5000

    auto launch_mm = [&](int SA, int SB, const u16* A0, const u16* A1, const u16* B0, const u16* B1,
                         float* Cc, const float* cbias, int M, int N, int Kpad,
                         int lda, int ldb, int ldc, size_t cstride, int Z) -> int {
        int kPerZ = CDIV(Kpad, Z * 32) * 32;
        int gz = CDIV(Kpad, kPerZ);
        dim3 g(CDIV(N, 128), CDIV(M, 128), gz);
        if (SA)      mm_nt<1, 0><<<g, 256, 0, stream>>>(A0, A1, B0, B1, Cc, cbias, M, N, lda, ldb, ldc, kPerZ, Kpad, cstride);
        else if (SB) mm_nt<0, 1><<<g, 256, 0, stream>>>(A0, A1, B0, B1, Cc, cbias, M, N, lda, ldb, ldc, kPerZ, Kpad, cstride);
        else         mm_nt<0, 0><<<g, 256, 0, stream>>>(A0, A1, B0, B1, Cc, cbias, M, N, lda, ldb, ldc, kPerZ, Kpad, cstride);
        return gz;
    };

    // gcn: y = act(dinv*(adjb @ (dinv*x@W)) + dinv^2*(x@W) + b), adjb padded [Mp][Np=Mp]
    auto run_gcn = [&](const u16* adjb, int n, int Np,
                       const float* x, int kin, const float* W, const float* bias,
                       const float* dinv, int relu, float* y, int Z) {
        gemm64<<<dim3(2, CDIV(n, 64)), 256, 0, stream>>>(x, W, xw, n, 128, kin, kin, 128, 128, nullptr, 0);
        scale_split_k<<<dim3(Np / 32, 4), 256, 0, stream>>>(xw, dinv, zhT, zlT, n, Np);
        int gz = launch_mm(0, 1, adjb, nullptr, zhT, zlT, partials, nullptr,
                           Np, 128, Np, Np, Np, 128, (size_t)Np * 128, Z);
        reduce_gcn_post_k<<<n, 128, 0, stream>>>(partials, gz, Np, xw, dinv, bias, y, relu);
    };

    auto run_pool = [&](const float* x, int n, int Np, int kNew, int KpNew, const float* pw,
                        const u16* srcb, const u16* srcbT, u16* adjNew, int* perm, int Z) {
        score_k<<<n, 128, 0, stream>>>(x, pw, scorev);
        int nsl = CDIV(n, 512);
        rank_partial_k<<<dim3(CDIV(n, 256), nsl), 256, 0, stream>>>(scorev, n, rankpart);
        scatter_topk_k<<<CDIV(n, 256), 256, 0, stream>>>(scorev, rankpart, nsl, n, kNew, perm, scv);
        pool_x_k<<<kNew, 128, 0, stream>>>(xa, x, perm, scv);
        gather2_b_k<<<dim3(kNew, 2), 256, 0, stream>>>(srcb, srcbT, Np, perm, G, HT, Np);
        int gz = launch_mm(0, 0, G, nullptr, HT, nullptr, partials, nullptr,
                           KpNew, KpNew, Np, Np, Np, KpNew, (size_t)KpNew * KpNew, Z);
        reduce_pool_k<<<KpNew, 256, 0, stream>>>(partials, gz, kNew, KpNew, adjNew);
    };

    // ---- build adjacency (padded fp32), convert to bf16 + bf16^T, dinv0 ----
    hipMemsetAsync(adj0, 0, (size_t)Np0 * Np0 * sizeof(float), stream);
    build_adj_k<<<CDIV(E, 256), 256, 0, stream>>>(ei, adj0, E, Np0);
    conv0_k<<<dim3(Np0 / 64, Np0 / 64), 256, 0, stream>>>(adj0, adj0b, adj0bT, Np0);
    rowsum_dinv_b_k<<<N0, 256, 0, stream>>>(adj0b, Np0, Np0, dinv0);

    // ---- initial GCN ----
    run_gcn(adj0b, N0, Np0, pos, 3, Wd0, bd0, dinv0, 1, x0, 10);

    // ---- down level 0: 5000 -> 2000 ----
    run_pool(x0, N0, Np0, K1, Kp1, pw0, adj0b, adj0bT, adj1b, perm0, 3);
    transpose_b_k<<<dim3(Kp1 / 64, Kp1 / 64), 256, 0, stream>>>(adj1b, adj1bT, Kp1);
    rowsum_dinv_b_k<<<K1, 256, 0, stream>>>(adj1b, Kp1, Kp1, dinv1);
    run_gcn(adj1b, K1, Kp1, xa, 128, Wd1, bd1, dinv1, 1, x1, 16);

    // ---- down level 1: 2000 -> 1000 ----
    run_pool(x1, K1, Kp1, K2, Kp2, pw1, adj1b, adj1bT, adj2b, perm1, 8);
    transpose_b_k<<<dim3(Kp2 / 64, Kp2 / 64), 256, 0, stream>>>(adj2b, adj2bT, Kp2);
    rowsum_dinv_b_k<<<K2, 256, 0, stream>>>(adj2b, Kp2, Kp2, dinv2);
    run_gcn(adj2b, K2, Kp2, xa, 128, Wd2, bd2, dinv2, 1, x2, 16);

    // ---- down level 2: 1000 -> 500 ----
    run_pool(x2, K2, Kp2, K3, Kp3, pw2, adj2b, adj2bT, adj3b, perm2, 8);
    rowsum_dinv_b_k<<<K3, 256, 0, stream>>>(adj3b, Kp3, Kp3, dinv3);
    run_gcn(adj3b, K3, Kp3, xa, 128, Wd3, bd3, dinv3, 1, xb, 8);           // xb: 500x128

    // ---- up i=0 (j=2) ----
    hipMemcpyAsync(xa, x2, (size_t)K2 * 128 * sizeof(float), hipMemcpyDeviceToDevice, stream);
    scatter_add_k<<<K3, 128, 0, stream>>>(xa, perm2, xb);
    run_gcn(adj2b, K2, Kp2, xa, 128, Wu0, bu0, dinv2, 1, xb, 16);          // xb: 1000x128

    // ---- up i=1 (j=1) ----
    hipMemcpyAsync(xa, x1, (size_t)K1 * 128 * sizeof(float), hipMemcpyDeviceToDevice, stream);
    scatter_add_k<<<K2, 128, 0, stream>>>(xa, perm1, xb);
    run_gcn(adj1b, K1, Kp1, xa, 128, Wu1, bu1, dinv1, 1, xb, 16);          // xb: 2000x128

    // ---- up i=2 (j=0), no relu ----
    hipMemcpyAsync(xa, x0, (size_t)N0 * 128 * sizeof(float), hipMemcpyDeviceToDevice, stream);
    scatter_add_k<<<K1, 128, 0, stream>>>(xa, perm0, xb);
    run_gcn(adj0b, N0, Np0, xa, 128, Wu2, bu2, dinv0, 0, xb, 10);          // xb: 5000x128

    // ---- MLP head (bias+relu fused in gemm64 epilogue) ----
    gemm64<<<dim3(2, CDIV(N0, 64)), 256, 0, stream>>>(xb, W1, xa, N0, 128, 128, 128, 128, 128, b1, 1);
    gemm64<<<dim3(2, CDIV(N0, 64)), 256, 0, stream>>>(xa, W2, xw, N0, 128, 128, 128, 128, 128, b2, 0);

    split_head_k<<<N0, 128, 0, stream>>>(xw, Ah, Al);
    convW3T_k<<<dim3(OUTCP / 64, 2), 256, 0, stream>>>(W3, W3T, OUTC, OUTCP);

    float* outp = (float*)d_out;
    launch_mm(1, 0, Ah, Al, W3T, nullptr, outp, b3, N0, OUTC, 128, 128, 128, OUTC, 0, 1);
    logsoftmax_k<<<N0, 256, OUTC * sizeof(float), stream>>>(outp, OUTC);
}

// Round 10
// 877.977 us; speedup vs baseline: 1.0623x; 1.0519x over previous
//
#include <hip/hip_runtime.h>
#include <cmath>

#define CDIV(a,b) (((a)+(b)-1)/(b))

using u16 = unsigned short;
using short8 = __attribute__((ext_vector_type(8))) short;
using f32x4 = __attribute__((ext_vector_type(4))) float;

__device__ __forceinline__ u16 f2b(float v) {
    union { float f; unsigned u; } x; x.f = v;
    unsigned r = x.u + 0x7fffu + ((x.u >> 16) & 1u);
    return (u16)(r >> 16);
}
__device__ __forceinline__ float b2f(u16 h) {
    union { unsigned u; float f; } x; x.u = ((unsigned)h) << 16;
    return x.f;
}

#if defined(__has_builtin)
#if __has_builtin(__builtin_amdgcn_global_load_lds)
#define HAS_GLL 1
#endif
#endif
#ifndef HAS_GLL
#define HAS_GLL 0
#endif

// async global->LDS, 16B per lane; LDS dest must be linear in lane id.
__device__ __forceinline__ void g2l(const u16* g, uint4* l) {
#if HAS_GLL
    __builtin_amdgcn_global_load_lds((const __attribute__((address_space(1))) void*)g,
                                     (__attribute__((address_space(3))) void*)l, 16, 0, 0);
#else
    *l = *(const uint4*)g;
#endif
}

// ----------------------------- build / norm -----------------------------

__global__ void build_adj_k(const int* __restrict__ ei, float* __restrict__ adj, int E, int ld) {
    int e = blockIdx.x * 256 + threadIdx.x;
    if (e < E) {
        int s = ei[e];
        int d = ei[E + e];
        atomicAdd(&adj[(size_t)s * ld + d], 1.0f);
    }
}

__global__ void rowsum_dinv_b_k(const u16* __restrict__ adjb, int ld, int n, float* __restrict__ dinv) {
    int i = blockIdx.x;
    __shared__ float red[256];
    const u16* row = adjb + (size_t)i * ld;
    float s = 0.f;
    for (int j = threadIdx.x; j < n; j += 256) s += b2f(row[j]);
    red[threadIdx.x] = s; __syncthreads();
    for (int w = 128; w > 0; w >>= 1) {
        if (threadIdx.x < w) red[threadIdx.x] += red[threadIdx.x + w];
        __syncthreads();
    }
    if (threadIdx.x == 0) dinv[i] = rsqrtf(red[0] + 1.0f);
}

// fp32 adj (padded, zero-filled) -> bf16 straight + bf16 transposed
__global__ void conv0_k(const float* __restrict__ in, u16* __restrict__ outS, u16* __restrict__ outT, int n) {
    __shared__ u16 t[64][65];
    int i0 = blockIdx.y * 64, j0 = blockIdx.x * 64;
    for (int e = threadIdx.x; e < 4096; e += 256) {
        int r = e >> 6, c = e & 63;
        u16 v = f2b(in[(size_t)(i0 + r) * n + j0 + c]);
        outS[(size_t)(i0 + r) * n + j0 + c] = v;
        t[r][c] = v;
    }
    __syncthreads();
    for (int e = threadIdx.x; e < 4096; e += 256) {
        int r = e >> 6, c = e & 63;
        outT[(size_t)(j0 + r) * n + i0 + c] = t[c][r];
    }
}

__global__ void transpose_b_k(const u16* __restrict__ in, u16* __restrict__ out, int n) {
    __shared__ u16 t[64][65];
    int i0 = blockIdx.y * 64, j0 = blockIdx.x * 64;
    for (int e = threadIdx.x; e < 4096; e += 256) {
        int r = e >> 6, c = e & 63;
        t[r][c] = in[(size_t)(i0 + r) * n + j0 + c];
    }
    __syncthreads();
    for (int e = threadIdx.x; e < 4096; e += 256) {
        int r = e >> 6, c = e & 63;
        out[(size_t)(j0 + r) * n + i0 + c] = t[c][r];
    }
}

// --------- MFMA GEMM, NT form, padded (no staging guards), gload_lds, BK=32 ---------
// LDS layout (512 x uint4 per matrix): idx = (R>>4)*64 + kg*16 + (R&15)
// Staging slot == thread id (linear, required by global_load_lds); fragment reads are
// 1KB-consecutive per 64-lane wave -> conflict-free. Global pointers hoisted, += 32/iter.
// XCD-aware chunked swizzle on the x-y plane when (gx*gy)%8==0 (bijective).

template<int SA, int SB>
__global__ __launch_bounds__(256) void mm_nt(const u16* __restrict__ A0, const u16* __restrict__ A1,
                                             const u16* __restrict__ B0, const u16* __restrict__ B1,
                                             float* __restrict__ C, const float* __restrict__ cbias,
                                             int M, int N, int lda, int ldb, int ldc,
                                             int kPerZ, int Kpad, size_t cstride) {
    __shared__ uint4 lds_t[(2 + SA + SB) * 512];
    uint4* Ab  = lds_t;
    uint4* A1b = lds_t + (SA ? 512 : 0);
    uint4* Bb  = lds_t + (1 + SA) * 512;
    uint4* B1b = Bb + (SB ? 512 : 0);

    int tid = threadIdx.x;

    // XCD-aware swizzle of the x-y plane (identity when plane not 8-divisible)
    int nx = gridDim.x, nxy = nx * gridDim.y;
    int bx = blockIdx.x, by = blockIdx.y;
    if ((nxy & 7) == 0) {
        int flat = by * nx + bx;
        int nf = (flat & 7) * (nxy >> 3) + (flat >> 3);
        bx = nf % nx; by = nf / nx;
    }
    int row0 = by * 128, col0 = bx * 128;

    int kbeg = blockIdx.z * kPerZ;
    int kend = min(kbeg + kPerZ, Kpad);
    C += (size_t)blockIdx.z * cstride;

    int wave = tid >> 6, lane = tid & 63;
    int wr = (wave >> 1) * 64, wc = (wave & 1) * 64;
    int lrow = lane & 15, kg = lane >> 4;

    // staging slots (two per thread)
    int tS0 = tid, tS1 = tid + 256;
    int R0 = ((tS0 >> 6) << 4) | (tS0 & 15), kc0 = (tS0 >> 4) & 3;
    int R1 = ((tS1 >> 6) << 4) | (tS1 & 15), kc1 = (tS1 >> 4) & 3;

    const u16* aP0 = A0 + (size_t)(row0 + R0) * lda + kbeg + kc0 * 8;
    const u16* aP1 = A0 + (size_t)(row0 + R1) * lda + kbeg + kc1 * 8;
    const u16* bP0 = B0 + (size_t)(col0 + R0) * ldb + kbeg + kc0 * 8;
    const u16* bP1 = B0 + (size_t)(col0 + R1) * ldb + kbeg + kc1 * 8;
    const u16* a1P0 = SA ? (A1 + (size_t)(row0 + R0) * lda + kbeg + kc0 * 8) : nullptr;
    const u16* a1P1 = SA ? (A1 + (size_t)(row0 + R1) * lda + kbeg + kc1 * 8) : nullptr;
    const u16* b1P0 = SB ? (B1 + (size_t)(col0 + R0) * ldb + kbeg + kc0 * 8) : nullptr;
    const u16* b1P1 = SB ? (B1 + (size_t)(col0 + R1) * ldb + kbeg + kc1 * 8) : nullptr;

    f32x4 acc[4][4] = {};

    for (int k0 = kbeg; k0 < kend; k0 += 32) {
        __syncthreads();
        g2l(aP0, Ab + tS0);
        g2l(aP1, Ab + tS1);
        if constexpr (SA) { g2l(a1P0, A1b + tS0); g2l(a1P1, A1b + tS1); }
        g2l(bP0, Bb + tS0);
        g2l(bP1, Bb + tS1);
        if constexpr (SB) { g2l(b1P0, B1b + tS0); g2l(b1P1, B1b + tS1); }
        __syncthreads();

        const short8* Ap  = (const short8*)Ab;
        const short8* A1p = (const short8*)A1b;
        const short8* Bp  = (const short8*)Bb;
        const short8* B1p = (const short8*)B1b;

        short8 a[4], a1[4], b[4], b1[4];
#pragma unroll
        for (int m = 0; m < 4; ++m) {
            int idx = (((wr >> 4) + m) << 6) | (kg << 4) | lrow;
            a[m] = Ap[idx];
            if constexpr (SA) a1[m] = A1p[idx];
        }
#pragma unroll
        for (int n = 0; n < 4; ++n) {
            int idx = (((wc >> 4) + n) << 6) | (kg << 4) | lrow;
            b[n] = Bp[idx];
            if constexpr (SB) b1[n] = B1p[idx];
        }
#pragma unroll
        for (int m = 0; m < 4; ++m)
#pragma unroll
            for (int n = 0; n < 4; ++n) {
                acc[m][n] = __builtin_amdgcn_mfma_f32_16x16x32_bf16(a[m], b[n], acc[m][n], 0, 0, 0);
                if constexpr (SA) acc[m][n] = __builtin_amdgcn_mfma_f32_16x16x32_bf16(a1[m], b[n], acc[m][n], 0, 0, 0);
                if constexpr (SB) acc[m][n] = __builtin_amdgcn_mfma_f32_16x16x32_bf16(a[m], b1[n], acc[m][n], 0, 0, 0);
            }

        aP0 += 32; aP1 += 32; bP0 += 32; bP1 += 32;
        if constexpr (SA) { a1P0 += 32; a1P1 += 32; }
        if constexpr (SB) { b1P0 += 32; b1P1 += 32; }
    }

#pragma unroll
    for (int m = 0; m < 4; ++m) {
        int rm = row0 + wr + m * 16 + kg * 4;
#pragma unroll
        for (int n = 0; n < 4; ++n) {
            int cc = col0 + wc + n * 16 + lrow;
            if (cc >= N) continue;
            float badd = cbias ? cbias[cc] : 0.f;
#pragma unroll
            for (int i = 0; i < 4; ++i) {
                int r = rm + i;
                if (r < M) C[(size_t)r * ldc + cc] = acc[m][n][i] + badd;
            }
        }
    }
}

// ----------------------------- fp32 gemm (small K only) -----------------------------

__global__ __launch_bounds__(256) void gemm64(const float* __restrict__ A, const float* __restrict__ B,
                                              float* __restrict__ C,
                                              int M, int N, int K, int lda, int ldb, int ldc,
                                              const float* __restrict__ bias, int relu) {
    __shared__ float As[16][65];
    __shared__ float Bs[16][65];
    int tid = threadIdx.x;
    int trow = tid / 16, tcol = tid % 16;
    int row0 = blockIdx.y * 64 + trow * 4;
    int col0 = blockIdx.x * 64 + tcol * 4;
    float acc[4][4] = {};
    int am = tid >> 2;
    int ak = (tid & 3) * 4;
    int bk = tid >> 4;
    int bn = (tid & 15) * 4;
    for (int k0 = 0; k0 < K; k0 += 16) {
        int gm = blockIdx.y * 64 + am;
#pragma unroll
        for (int u = 0; u < 4; ++u) {
            int gk = k0 + ak + u;
            As[ak + u][am] = (gm < M && gk < K) ? A[(size_t)gm * lda + gk] : 0.f;
        }
        int gbk = k0 + bk;
#pragma unroll
        for (int u = 0; u < 4; ++u) {
            int gn = blockIdx.x * 64 + bn + u;
            Bs[bk][bn + u] = (gbk < K && gn < N) ? B[(size_t)gbk * ldb + gn] : 0.f;
        }
        __syncthreads();
#pragma unroll
        for (int kk = 0; kk < 16; ++kk) {
            float a[4], b[4];
#pragma unroll
            for (int i = 0; i < 4; ++i) a[i] = As[kk][trow * 4 + i];
#pragma unroll
            for (int j = 0; j < 4; ++j) b[j] = Bs[kk][tcol * 4 + j];
#pragma unroll
            for (int i = 0; i < 4; ++i)
#pragma unroll
                for (int j = 0; j < 4; ++j) acc[i][j] += a[i] * b[j];
        }
        __syncthreads();
    }
#pragma unroll
    for (int i = 0; i < 4; ++i) {
        int r = row0 + i;
        if (r >= M) continue;
#pragma unroll
        for (int j = 0; j < 4; ++j) {
            int c = col0 + j;
            if (c < N) {
                float v = acc[i][j] + (bias ? bias[c] : 0.f);
                if (relu) v = fmaxf(v, 0.f);
                C[(size_t)r * ldc + c] = v;
            }
        }
    }
}

// ----------------------------- GCN glue -----------------------------

// transposing split: zhT/zlT[f][i] = bf16 hi/lo of dinv[i]*xw[i][f]; zero-fill i in [M, ldz)
__global__ void scale_split_k(const float* __restrict__ xw, const float* __restrict__ dinv,
                              u16* __restrict__ zhT, u16* __restrict__ zlT, int M, int ldz) {
    __shared__ float t[32][33];
    int i0 = blockIdx.x * 32, f0 = blockIdx.y * 32;
#pragma unroll
    for (int it = 0; it < 4; ++it) {
        int r = it * 8 + (threadIdx.x >> 5);
        int c = threadIdx.x & 31;
        int i = i0 + r;
        t[r][c] = (i < M) ? dinv[i] * xw[(size_t)i * 128 + f0 + c] : 0.f;
    }
    __syncthreads();
#pragma unroll
    for (int it = 0; it < 4; ++it) {
        int r = it * 8 + (threadIdx.x >> 5);
        int c = threadIdx.x & 31;
        int f = f0 + r, i = i0 + c;
        float v = t[c][r];
        u16 h = f2b(v);
        zhT[(size_t)f * ldz + i] = h;
        zlT[(size_t)f * ldz + i] = f2b(v - b2f(h));
    }
}

__global__ void reduce_gcn_post_k(const float* __restrict__ part, int Z, int Mp,
                                  const float* __restrict__ xw, const float* __restrict__ dinv,
                                  const float* __restrict__ bias, float* __restrict__ y, int relu) {
    int i = blockIdx.x, f = threadIdx.x;
    size_t idx = (size_t)i * 128 + f;
    float s = 0.f;
    for (int z = 0; z < Z; ++z) s += part[(size_t)z * Mp * 128 + idx];
    float di = dinv[i];
    float v = di * s + di * di * xw[idx] + bias[f];
    y[idx] = relu ? fmaxf(v, 0.f) : v;
}

// ----------------------------- pooling -----------------------------

// score with fused ||pw||
__global__ void score_k(const float* __restrict__ x, const float* __restrict__ pw,
                        float* __restrict__ score) {
    int i = blockIdx.x;
    __shared__ float red[128], red2[128];
    float p = pw[threadIdx.x];
    red[threadIdx.x]  = x[(size_t)i * 128 + threadIdx.x] * p;
    red2[threadIdx.x] = p * p;
    __syncthreads();
    for (int s = 64; s > 0; s >>= 1) {
        if (threadIdx.x < s) { red[threadIdx.x] += red[threadIdx.x + s]; red2[threadIdx.x] += red2[threadIdx.x + s]; }
        __syncthreads();
    }
    if (threadIdx.x == 0) score[i] = tanhf(red[0] / sqrtf(red2[0]));
}

// per-slice stable-rank partial counts (no atomics, no memset)
__global__ __launch_bounds__(256) void rank_partial_k(const float* __restrict__ score, int n,
                                                      int* __restrict__ rankpart) {
    __shared__ float s_sh[512];
    int i = blockIdx.x * 256 + threadIdx.x;
    int jbase = blockIdx.y * 512;
    float si = (i < n) ? score[i] : -3.0f;
    for (int t = threadIdx.x; t < 512; t += 256) {
        int j = jbase + t;
        s_sh[t] = (j < n) ? score[j] : -3.0f;
    }
    __syncthreads();
    int cnt = 0;
#pragma unroll 16
    for (int t = 0; t < 512; ++t) {
        float sj = s_sh[t];
        cnt += (sj > si) || (sj == si && (jbase + t) < i);
    }
    if (i < n) rankpart[blockIdx.y * n + i] = cnt;
}

__global__ void scatter_topk_k(const float* __restrict__ score, const int* __restrict__ rankpart,
                               int nsl, int n, int k, int* __restrict__ perm, float* __restrict__ sc) {
    int i = blockIdx.x * 256 + threadIdx.x;
    if (i >= n) return;
    int r = 0;
    for (int s = 0; s < nsl; ++s) r += rankpart[s * n + i];
    if (r < k) { perm[r] = i; sc[r] = score[i]; }
}

__global__ void pool_x_k(float* __restrict__ xo, const float* __restrict__ xi,
                         const int* __restrict__ perm, const float* __restrict__ sc) {
    int a = blockIdx.x, f = threadIdx.x;
    xo[(size_t)a * 128 + f] = xi[(size_t)perm[a] * 128 + f] * sc[a];
}

// two gathers in one dispatch: dst row = src[perm[row], :] with [row][perm[row]] = 1
__global__ void gather2_b_k(const u16* __restrict__ src0, const u16* __restrict__ src1,
                            int ldsrc, const int* __restrict__ perm,
                            u16* __restrict__ dst0, u16* __restrict__ dst1, int width) {
    const u16* src = blockIdx.y ? src1 : src0;
    u16* dst = blockIdx.y ? dst1 : dst0;
    int row = blockIdx.x;
    int p = perm[row];
    const uint4* s4 = (const uint4*)(src + (size_t)p * ldsrc);
    uint4* d4 = (uint4*)(dst + (size_t)row * width);
    int n8 = width >> 3;
    for (int j = threadIdx.x; j < n8; j += 256) d4[j] = s4[j];
    __syncthreads();
    if (threadIdx.x == 0) dst[(size_t)row * width + p] = 0x3F80;  // 1.0 bf16
}

// sum Z slices, zero diag, zero-pad rows/cols >= k (out is [Mp][Mp])
__global__ void reduce_pool_k(const float* __restrict__ part, int Z, int k, int Mp, u16* __restrict__ out) {
    int row = blockIdx.x;
    for (int j = threadIdx.x; j < Mp; j += 256) {
        float s = 0.f;
        if (row < k && j < k) {
            for (int z = 0; z < Z; ++z) s += part[(size_t)z * Mp * Mp + (size_t)row * Mp + j];
            if (j == row) s = 0.f;
        }
        out[(size_t)row * Mp + j] = f2b(s);
    }
}

__global__ void scatter_add_k(float* __restrict__ xdst, const int* __restrict__ perm,
                              const float* __restrict__ xsrc) {
    int a = blockIdx.x, f = threadIdx.x;
    xdst[(size_t)perm[a] * 128 + f] += xsrc[(size_t)a * 128 + f];
}

// ----------------------------- head -----------------------------

__global__ void split_head_k(const float* __restrict__ x, u16* __restrict__ Ah, u16* __restrict__ Al) {
    int i = blockIdx.x, f = threadIdx.x;
    size_t idx = (size_t)i * 128 + f;
    float v = x[idx];
    u16 h = f2b(v);
    Ah[idx] = h;
    Al[idx] = f2b(v - b2f(h));
}

// W3 [128][Nc] fp32 -> W3T [Ncp][128] bf16, rows [Nc,Ncp) zeroed
__global__ void convW3T_k(const float* __restrict__ W3, u16* __restrict__ W3T, int Nc, int Ncp) {
    __shared__ float t[64][65];
    int k0 = blockIdx.y * 64, n0 = blockIdx.x * 64;
    for (int e = threadIdx.x; e < 4096; e += 256) {
        int r = e >> 6, c = e & 63;
        t[r][c] = (k0 + r < 128 && n0 + c < Nc) ? W3[(size_t)(k0 + r) * Nc + n0 + c] : 0.f;
    }
    __syncthreads();
    for (int e = threadIdx.x; e < 4096; e += 256) {
        int r = e >> 6, c = e & 63;
        int nn = n0 + r, kk = k0 + c;
        if (nn < Ncp) W3T[(size_t)nn * 128 + kk] = f2b(t[c][r]);
    }
}

// register-resident log-softmax over C=6890 columns, one row per block.
// 27 elements/thread in registers (static indexing), two 256-wide LDS reductions.
__global__ __launch_bounds__(256) void logsoftmax_k(float* __restrict__ out) {
    const int C = 6890;
    const int CPT = 27;                       // 256*27 = 6912 >= 6890
    int row = blockIdx.x;
    float* rowp = out + (size_t)row * C;
    __shared__ float red[256];

    float v[CPT];
    float mx = -1e30f;
#pragma unroll
    for (int u = 0; u < CPT; ++u) {
        int c = threadIdx.x + u * 256;
        v[u] = (c < C) ? rowp[c] : -1e30f;
        mx = fmaxf(mx, v[u]);
    }
    red[threadIdx.x] = mx; __syncthreads();
    for (int s = 128; s > 0; s >>= 1) {
        if (threadIdx.x < s) red[threadIdx.x] = fmaxf(red[threadIdx.x], red[threadIdx.x + s]);
        __syncthreads();
    }
    float m = red[0];
    __syncthreads();

    float sum = 0.f;
#pragma unroll
    for (int u = 0; u < CPT; ++u) sum += __expf(v[u] - m);   // pad lanes: exp(-huge)=0
    red[threadIdx.x] = sum; __syncthreads();
    for (int s = 128; s > 0; s >>= 1) {
        if (threadIdx.x < s) red[threadIdx.x] += red[threadIdx.x + s];
        __syncthreads();
    }
    float ls = m + logf(red[0]);

#pragma unroll
    for (int u = 0; u < CPT; ++u) {
        int c = threadIdx.x + u * 256;
        if (c < C) rowp[c] = v[u] - ls;
    }
}

// ----------------------------- entry -----------------------------

extern "C" void kernel_launch(void* const* d_in, const int* in_sizes, int n_in,
                              void* d_out, int out_size, void* d_ws, size_t ws_size,
                              hipStream_t stream) {
    const int N0 = 5000, K1 = 2000, K2 = 1000, K3 = 500, E = 80000, OUTC = 6890;
    const int Np0 = 5120, Kp1 = 2048, Kp2 = 1024, Kp3 = 512, OUTCP = 6912;
    (void)in_sizes; (void)n_in; (void)out_size; (void)ws_size;

    const float* pos = (const float*)d_in[0];
    const int*   ei  = (const int*)d_in[1];
    const float* Wd0 = (const float*)d_in[2];  const float* bd0 = (const float*)d_in[3];
    const float* Wd1 = (const float*)d_in[4];  const float* bd1 = (const float*)d_in[5];
    const float* Wd2 = (const float*)d_in[6];  const float* bd2 = (const float*)d_in[7];
    const float* Wd3 = (const float*)d_in[8];  const float* bd3 = (const float*)d_in[9];
    const float* pw0 = (const float*)d_in[10];
    const float* pw1 = (const float*)d_in[11];
    const float* pw2 = (const float*)d_in[12];
    const float* Wu0 = (const float*)d_in[13]; const float* bu0 = (const float*)d_in[14];
    const float* Wu1 = (const float*)d_in[15]; const float* bu1 = (const float*)d_in[16];
    const float* Wu2 = (const float*)d_in[17]; const float* bu2 = (const float*)d_in[18];
    const float* W1  = (const float*)d_in[19]; const float* b1  = (const float*)d_in[20];
    const float* W2  = (const float*)d_in[21]; const float* b2  = (const float*)d_in[22];
    const float* W3  = (const float*)d_in[23]; const float* b3  = (const float*)d_in[24];

    float* w = (float*)d_ws;
    size_t off = 0;
    auto alloc = [&](size_t nel) { float* p = w + off; off += nel; return p; };

    // pool region (26.22M floats = 5120^2): adj0 fp32 transiently; then
    //   partials [0,13M) | G [13M,18.25M) | HT [18.25M,23.5M)
    //   zhT/zlT overlap G (GCN phase only); Ah/Al overlap partials (head phase only)
    float* pool = alloc(26220000);
    float* adj0 = pool;
    float* partials = pool;
    u16* G   = (u16*)(pool + 13000000);
    u16* HT  = (u16*)(pool + 18250000);
    u16* zhT = (u16*)(pool + 13000000);
    u16* zlT = (u16*)(pool + 13400000);
    u16* Ah  = (u16*)(pool);
    u16* Al  = (u16*)(pool + 400000);

    u16* adj0b  = (u16*)alloc(13107200);     // 5120 x 5120
    u16* adj0bT = (u16*)alloc(13107200);
    u16* adj1b  = (u16*)alloc(2097152);      // 2048 x 2048
    u16* adj1bT = (u16*)alloc(2097152);
    u16* adj2b  = (u16*)alloc(524288);       // 1024 x 1024
    u16* adj2bT = (u16*)alloc(524288);
    u16* adj3b  = (u16*)alloc(131072);       // 512 x 512
    u16* W3T    = (u16*)alloc(442368);       // 6912 x 128

    float* x0 = alloc((size_t)N0 * 128);
    float* x1 = alloc((size_t)K1 * 128);
    float* x2 = alloc((size_t)K2 * 128);
    float* xa = alloc((size_t)N0 * 128);
    float* xb = alloc((size_t)N0 * 128);
    float* xw = alloc((size_t)N0 * 128);
    float* dinv0 = alloc(N0); float* dinv1 = alloc(K1); float* dinv2 = alloc(K2); float* dinv3 = alloc(K3);
    float* scorev = alloc(N0);
    float* scv    = alloc(K1);
    int* perm0 = (int*)alloc(K1);
    int* perm1 = (int*)alloc(K2);
    int* perm2 = (int*)alloc(K3);
    int* rankpart = (int*)alloc(50048);      // up to 10 slices x 5000

    auto launch_mm = [&](int SA, int SB, const u16* A0, const u16* A1, const u16* B0, const u16* B1,
                         float* Cc, const float* cbias, int M, int N, int Kpad,
                         int lda, int ldb, int ldc, size_t cstride, int Z) -> int {
        int kPerZ = CDIV(Kpad, Z * 32) * 32;
        int gz = CDIV(Kpad, kPerZ);
        dim3 g(CDIV(N, 128), CDIV(M, 128), gz);
        if (SA)      mm_nt<1, 0><<<g, 256, 0, stream>>>(A0, A1, B0, B1, Cc, cbias, M, N, lda, ldb, ldc, kPerZ, Kpad, cstride);
        else if (SB) mm_nt<0, 1><<<g, 256, 0, stream>>>(A0, A1, B0, B1, Cc, cbias, M, N, lda, ldb, ldc, kPerZ, Kpad, cstride);
        else         mm_nt<0, 0><<<g, 256, 0, stream>>>(A0, A1, B0, B1, Cc, cbias, M, N, lda, ldb, ldc, kPerZ, Kpad, cstride);
        return gz;
    };

    // gcn: y = act(dinv*(adjb @ (dinv*x@W)) + dinv^2*(x@W) + b), adjb padded [Mp][Np=Mp]
    auto run_gcn = [&](const u16* adjb, int n, int Np,
                       const float* x, int kin, const float* W, const float* bias,
                       const float* dinv, int relu, float* y, int Z) {
        gemm64<<<dim3(2, CDIV(n, 64)), 256, 0, stream>>>(x, W, xw, n, 128, kin, kin, 128, 128, nullptr, 0);
        scale_split_k<<<dim3(Np / 32, 4), 256, 0, stream>>>(xw, dinv, zhT, zlT, n, Np);
        int gz = launch_mm(0, 1, adjb, nullptr, zhT, zlT, partials, nullptr,
                           Np, 128, Np, Np, Np, 128, (size_t)Np * 128, Z);
        reduce_gcn_post_k<<<n, 128, 0, stream>>>(partials, gz, Np, xw, dinv, bias, y, relu);
    };

    auto run_pool = [&](const float* x, int n, int Np, int kNew, int KpNew, const float* pw,
                        const u16* srcb, const u16* srcbT, u16* adjNew, int* perm, int Z) {
        score_k<<<n, 128, 0, stream>>>(x, pw, scorev);
        int nsl = CDIV(n, 512);
        rank_partial_k<<<dim3(CDIV(n, 256), nsl), 256, 0, stream>>>(scorev, n, rankpart);
        scatter_topk_k<<<CDIV(n, 256), 256, 0, stream>>>(scorev, rankpart, nsl, n, kNew, perm, scv);
        pool_x_k<<<kNew, 128, 0, stream>>>(xa, x, perm, scv);
        gather2_b_k<<<dim3(kNew, 2), 256, 0, stream>>>(srcb, srcbT, Np, perm, G, HT, Np);
        int gz = launch_mm(0, 0, G, nullptr, HT, nullptr, partials, nullptr,
                           KpNew, KpNew, Np, Np, Np, KpNew, (size_t)KpNew * KpNew, Z);
        reduce_pool_k<<<KpNew, 256, 0, stream>>>(partials, gz, kNew, KpNew, adjNew);
    };

    // ---- build adjacency (padded fp32), convert to bf16 + bf16^T, dinv0 ----
    hipMemsetAsync(adj0, 0, (size_t)Np0 * Np0 * sizeof(float), stream);
    build_adj_k<<<CDIV(E, 256), 256, 0, stream>>>(ei, adj0, E, Np0);
    conv0_k<<<dim3(Np0 / 64, Np0 / 64), 256, 0, stream>>>(adj0, adj0b, adj0bT, Np0);
    rowsum_dinv_b_k<<<N0, 256, 0, stream>>>(adj0b, Np0, Np0, dinv0);

    // ---- initial GCN ----
    run_gcn(adj0b, N0, Np0, pos, 3, Wd0, bd0, dinv0, 1, x0, 10);

    // ---- down level 0: 5000 -> 2000 ----
    run_pool(x0, N0, Np0, K1, Kp1, pw0, adj0b, adj0bT, adj1b, perm0, 3);
    transpose_b_k<<<dim3(Kp1 / 64, Kp1 / 64), 256, 0, stream>>>(adj1b, adj1bT, Kp1);
    rowsum_dinv_b_k<<<K1, 256, 0, stream>>>(adj1b, Kp1, Kp1, dinv1);
    run_gcn(adj1b, K1, Kp1, xa, 128, Wd1, bd1, dinv1, 1, x1, 16);

    // ---- down level 1: 2000 -> 1000 ----
    run_pool(x1, K1, Kp1, K2, Kp2, pw1, adj1b, adj1bT, adj2b, perm1, 8);
    transpose_b_k<<<dim3(Kp2 / 64, Kp2 / 64), 256, 0, stream>>>(adj2b, adj2bT, Kp2);
    rowsum_dinv_b_k<<<K2, 256, 0, stream>>>(adj2b, Kp2, Kp2, dinv2);
    run_gcn(adj2b, K2, Kp2, xa, 128, Wd2, bd2, dinv2, 1, x2, 16);

    // ---- down level 2: 1000 -> 500 ----
    run_pool(x2, K2, Kp2, K3, Kp3, pw2, adj2b, adj2bT, adj3b, perm2, 8);
    rowsum_dinv_b_k<<<K3, 256, 0, stream>>>(adj3b, Kp3, Kp3, dinv3);
    run_gcn(adj3b, K3, Kp3, xa, 128, Wd3, bd3, dinv3, 1, xb, 8);           // xb: 500x128

    // ---- up i=0 (j=2) ----
    hipMemcpyAsync(xa, x2, (size_t)K2 * 128 * sizeof(float), hipMemcpyDeviceToDevice, stream);
    scatter_add_k<<<K3, 128, 0, stream>>>(xa, perm2, xb);
    run_gcn(adj2b, K2, Kp2, xa, 128, Wu0, bu0, dinv2, 1, xb, 16);          // xb: 1000x128

    // ---- up i=1 (j=1) ----
    hipMemcpyAsync(xa, x1, (size_t)K1 * 128 * sizeof(float), hipMemcpyDeviceToDevice, stream);
    scatter_add_k<<<K2, 128, 0, stream>>>(xa, perm1, xb);
    run_gcn(adj1b, K1, Kp1, xa, 128, Wu1, bu1, dinv1, 1, xb, 16);          // xb: 2000x128

    // ---- up i=2 (j=0), no relu ----
    hipMemcpyAsync(xa, x0, (size_t)N0 * 128 * sizeof(float), hipMemcpyDeviceToDevice, stream);
    scatter_add_k<<<K1, 128, 0, stream>>>(xa, perm0, xb);
    run_gcn(adj0b, N0, Np0, xa, 128, Wu2, bu2, dinv0, 0, xb, 10);          // xb: 5000x128

    // ---- MLP head (bias+relu fused in gemm64 epilogue) ----
    gemm64<<<dim3(2, CDIV(N0, 64)), 256, 0, stream>>>(xb, W1, xa, N0, 128, 128, 128, 128, 128, b1, 1);
    gemm64<<<dim3(2, CDIV(N0, 64)), 256, 0, stream>>>(xa, W2, xw, N0, 128, 128, 128, 128, 128, b2, 0);

    split_head_k<<<N0, 128, 0, stream>>>(xw, Ah, Al);
    convW3T_k<<<dim3(OUTCP / 64, 2), 256, 0, stream>>>(W3, W3T, OUTC, OUTCP);

    float* outp = (float*)d_out;
    launch_mm(1, 0, Ah, Al, W3T, nullptr, outp, b3, N0, OUTC, 128, 128, 128, OUTC, 0, 1);
    logsoftmax_k<<<N0, 256, 0, stream>>>(outp);
}

// Round 11
// 817.122 us; speedup vs baseline: 1.1414x; 1.0745x over previous
//
#include <hip/hip_runtime.h>
#include <cmath>

#define CDIV(a,b) (((a)+(b)-1)/(b))

using u16 = unsigned short;
using short8 = __attribute__((ext_vector_type(8))) short;
using f32x4 = __attribute__((ext_vector_type(4))) float;

__device__ __forceinline__ u16 f2b(float v) {
    union { float f; unsigned u; } x; x.f = v;
    unsigned r = x.u + 0x7fffu + ((x.u >> 16) & 1u);
    return (u16)(r >> 16);
}
__device__ __forceinline__ float b2f(u16 h) {
    union { unsigned u; float f; } x; x.u = ((unsigned)h) << 16;
    return x.f;
}

#if defined(__has_builtin)
#if __has_builtin(__builtin_amdgcn_global_load_lds)
#define HAS_GLL 1
#endif
#endif
#ifndef HAS_GLL
#define HAS_GLL 0
#endif

__device__ __forceinline__ void g2l(const u16* g, uint4* l) {
#if HAS_GLL
    __builtin_amdgcn_global_load_lds((const __attribute__((address_space(1))) void*)g,
                                     (__attribute__((address_space(3))) void*)l, 16, 0, 0);
#else
    *l = *(const uint4*)g;
#endif
}

// ----------------------------- build / norm -----------------------------

__global__ void build_adj_k(const int* __restrict__ ei, float* __restrict__ adj, int E, int ld) {
    int e = blockIdx.x * 256 + threadIdx.x;
    if (e < E) {
        int s = ei[e];
        int d = ei[E + e];
        atomicAdd(&adj[(size_t)s * ld + d], 1.0f);
    }
}

__global__ void rowsum_dinv_b_k(const u16* __restrict__ adjb, int ld, int n, float* __restrict__ dinv) {
    int i = blockIdx.x;
    __shared__ float red[256];
    const u16* row = adjb + (size_t)i * ld;
    float s = 0.f;
    for (int j = threadIdx.x; j < n; j += 256) s += b2f(row[j]);
    red[threadIdx.x] = s; __syncthreads();
    for (int w = 128; w > 0; w >>= 1) {
        if (threadIdx.x < w) red[threadIdx.x] += red[threadIdx.x + w];
        __syncthreads();
    }
    if (threadIdx.x == 0) dinv[i] = rsqrtf(red[0] + 1.0f);
}

// fp32 (padded, zero-filled) -> bf16, elementwise, float4 vectorized
__global__ void convS_k(const float* __restrict__ in, u16* __restrict__ out, size_t n4) {
    size_t i = (size_t)blockIdx.x * 256 + threadIdx.x;
    if (i < n4) {
        float4 v = ((const float4*)in)[i];
        ushort4 o;
        o.x = f2b(v.x); o.y = f2b(v.y); o.z = f2b(v.z); o.w = f2b(v.w);
        ((ushort4*)out)[i] = o;
    }
}

__global__ void transpose_b_k(const u16* __restrict__ in, u16* __restrict__ out, int n) {
    __shared__ u16 t[64][65];
    int i0 = blockIdx.y * 64, j0 = blockIdx.x * 64;
    for (int e = threadIdx.x; e < 4096; e += 256) {
        int r = e >> 6, c = e & 63;
        t[r][c] = in[(size_t)(i0 + r) * n + j0 + c];
    }
    __syncthreads();
    for (int e = threadIdx.x; e < 4096; e += 256) {
        int r = e >> 6, c = e & 63;
        out[(size_t)(j0 + r) * n + i0 + c] = t[c][r];
    }
}

// ----------------------------- sparse pool-0 (CSR + SpGEMM, exact integers) --------

__global__ void csr_cnt_k(const int* __restrict__ ei, int E, int* __restrict__ rowcnt) {
    int e = blockIdx.x * 256 + threadIdx.x;
    if (e < E) {
        int u = ei[e], v = ei[E + e];
        if (u != v) atomicAdd(&rowcnt[u], 1);
    }
}

// single-block Hillis-Steele scan of n<=5120 ints -> exclusive rowptr[n+1]
__global__ __launch_bounds__(1024) void prefix_k(const int* __restrict__ cnt, int* __restrict__ ptr, int n) {
    __shared__ int buf[5120];
    for (int i = threadIdx.x; i < 5120; i += 1024) buf[i] = (i < n) ? cnt[i] : 0;
    __syncthreads();
    for (int d = 1; d < 5120; d <<= 1) {
        int vals[5];
#pragma unroll
        for (int c = 0; c < 5; ++c) {
            int i = threadIdx.x + c * 1024;
            vals[c] = (i >= d) ? buf[i - d] : 0;
        }
        __syncthreads();
#pragma unroll
        for (int c = 0; c < 5; ++c) {
            int i = threadIdx.x + c * 1024;
            buf[i] += vals[c];
        }
        __syncthreads();
    }
    for (int i = threadIdx.x; i <= n; i += 1024) ptr[i] = (i == 0) ? 0 : buf[i - 1];
}

__global__ void csr_fill_k(const int* __restrict__ ei, int E, const int* __restrict__ rowptr,
                           int* __restrict__ fill, int* __restrict__ cols) {
    int e = blockIdx.x * 256 + threadIdx.x;
    if (e < E) {
        int u = ei[e], v = ei[E + e];
        if (u != v) {
            int p = rowptr[u] + atomicAdd(&fill[u], 1);
            cols[p] = v;
        }
    }
}

__global__ void inv_k(const int* __restrict__ perm, int k, int* __restrict__ inv) {
    int r = blockIdx.x * 256 + threadIdx.x;
    if (r < k) inv[perm[r]] = r;
}

// A2[a][b] = sum over (pa->k, k->pb) pairs + 2*B[pa][pb]; exact integer atomics.
__global__ __launch_bounds__(256) void spgemm_k(const int* __restrict__ perm, const int* __restrict__ rowptr,
                                                const int* __restrict__ cols, const int* __restrict__ inv,
                                                int* __restrict__ A2, int ldo) {
    __shared__ int nb[256];
    __shared__ int degs;
    int a = blockIdx.x;
    int pa = perm[a];
    int s = rowptr[pa], epos = rowptr[pa + 1];
    int d = epos - s;
    if (threadIdx.x == 0) degs = d > 256 ? 256 : d;
    if (threadIdx.x < d && threadIdx.x < 256) nb[threadIdx.x] = cols[s + threadIdx.x];
    __syncthreads();
    int* rowA2 = A2 + (size_t)a * ldo;
    for (int p = s + threadIdx.x; p < epos; p += 256) {
        int b = inv[cols[p]];
        if (b >= 0) atomicAdd(&rowA2[b], 2);
    }
    int dd = degs;
    for (int j = 0; j < dd; ++j) {
        int kk = nb[j];
        int s2 = rowptr[kk], e2 = rowptr[kk + 1];
        for (int p = s2 + threadIdx.x; p < e2; p += 256) {
            int b = inv[cols[p]];
            if (b >= 0) atomicAdd(&rowA2[b], 1);
        }
    }
}

// int counts -> bf16 padded adj, diag + pad zeroed
__global__ void conv_spg_k(const int* __restrict__ A2, int kNew, int Mp, u16* __restrict__ out) {
    int r = blockIdx.x;
    for (int j = threadIdx.x; j < Mp; j += 256) {
        int v = 0;
        if (r < kNew && j < kNew && j != r) v = A2[(size_t)r * Mp + j];
        out[(size_t)r * Mp + j] = f2b((float)v);
    }
}

// --------- MFMA GEMM, NT form, padded (no staging guards), gload_lds, BK=32 ---------

template<int SA, int SB>
__global__ __launch_bounds__(256) void mm_nt(const u16* __restrict__ A0, const u16* __restrict__ A1,
                                             const u16* __restrict__ B0, const u16* __restrict__ B1,
                                             float* __restrict__ C, const float* __restrict__ cbias,
                                             int M, int N, int lda, int ldb, int ldc,
                                             int kPerZ, int Kpad, size_t cstride) {
    __shared__ uint4 lds_t[(2 + SA + SB) * 512];
    uint4* Ab  = lds_t;
    uint4* A1b = lds_t + (SA ? 512 : 0);
    uint4* Bb  = lds_t + (1 + SA) * 512;
    uint4* B1b = Bb + (SB ? 512 : 0);

    int tid = threadIdx.x;

    int nx = gridDim.x, nxy = nx * gridDim.y;
    int bx = blockIdx.x, by = blockIdx.y;
    if ((nxy & 7) == 0) {
        int flat = by * nx + bx;
        int nf = (flat & 7) * (nxy >> 3) + (flat >> 3);
        bx = nf % nx; by = nf / nx;
    }
    int row0 = by * 128, col0 = bx * 128;

    int kbeg = blockIdx.z * kPerZ;
    int kend = min(kbeg + kPerZ, Kpad);
    C += (size_t)blockIdx.z * cstride;

    int wave = tid >> 6, lane = tid & 63;
    int wr = (wave >> 1) * 64, wc = (wave & 1) * 64;
    int lrow = lane & 15, kg = lane >> 4;

    int tS0 = tid, tS1 = tid + 256;
    int R0 = ((tS0 >> 6) << 4) | (tS0 & 15), kc0 = (tS0 >> 4) & 3;
    int R1 = ((tS1 >> 6) << 4) | (tS1 & 15), kc1 = (tS1 >> 4) & 3;

    const u16* aP0 = A0 + (size_t)(row0 + R0) * lda + kbeg + kc0 * 8;
    const u16* aP1 = A0 + (size_t)(row0 + R1) * lda + kbeg + kc1 * 8;
    const u16* bP0 = B0 + (size_t)(col0 + R0) * ldb + kbeg + kc0 * 8;
    const u16* bP1 = B0 + (size_t)(col0 + R1) * ldb + kbeg + kc1 * 8;
    const u16* a1P0 = SA ? (A1 + (size_t)(row0 + R0) * lda + kbeg + kc0 * 8) : nullptr;
    const u16* a1P1 = SA ? (A1 + (size_t)(row0 + R1) * lda + kbeg + kc1 * 8) : nullptr;
    const u16* b1P0 = SB ? (B1 + (size_t)(col0 + R0) * ldb + kbeg + kc0 * 8) : nullptr;
    const u16* b1P1 = SB ? (B1 + (size_t)(col0 + R1) * ldb + kbeg + kc1 * 8) : nullptr;

    f32x4 acc[4][4] = {};

    for (int k0 = kbeg; k0 < kend; k0 += 32) {
        __syncthreads();
        g2l(aP0, Ab + tS0);
        g2l(aP1, Ab + tS1);
        if constexpr (SA) { g2l(a1P0, A1b + tS0); g2l(a1P1, A1b + tS1); }
        g2l(bP0, Bb + tS0);
        g2l(bP1, Bb + tS1);
        if constexpr (SB) { g2l(b1P0, B1b + tS0); g2l(b1P1, B1b + tS1); }
        __syncthreads();

        const short8* Ap  = (const short8*)Ab;
        const short8* A1p = (const short8*)A1b;
        const short8* Bp  = (const short8*)Bb;
        const short8* B1p = (const short8*)B1b;

        short8 a[4], a1[4], b[4], b1[4];
#pragma unroll
        for (int m = 0; m < 4; ++m) {
            int idx = (((wr >> 4) + m) << 6) | (kg << 4) | lrow;
            a[m] = Ap[idx];
            if constexpr (SA) a1[m] = A1p[idx];
        }
#pragma unroll
        for (int n = 0; n < 4; ++n) {
            int idx = (((wc >> 4) + n) << 6) | (kg << 4) | lrow;
            b[n] = Bp[idx];
            if constexpr (SB) b1[n] = B1p[idx];
        }
#pragma unroll
        for (int m = 0; m < 4; ++m)
#pragma unroll
            for (int n = 0; n < 4; ++n) {
                acc[m][n] = __builtin_amdgcn_mfma_f32_16x16x32_bf16(a[m], b[n], acc[m][n], 0, 0, 0);
                if constexpr (SA) acc[m][n] = __builtin_amdgcn_mfma_f32_16x16x32_bf16(a1[m], b[n], acc[m][n], 0, 0, 0);
                if constexpr (SB) acc[m][n] = __builtin_amdgcn_mfma_f32_16x16x32_bf16(a[m], b1[n], acc[m][n], 0, 0, 0);
            }

        aP0 += 32; aP1 += 32; bP0 += 32; bP1 += 32;
        if constexpr (SA) { a1P0 += 32; a1P1 += 32; }
        if constexpr (SB) { b1P0 += 32; b1P1 += 32; }
    }

#pragma unroll
    for (int m = 0; m < 4; ++m) {
        int rm = row0 + wr + m * 16 + kg * 4;
#pragma unroll
        for (int n = 0; n < 4; ++n) {
            int cc = col0 + wc + n * 16 + lrow;
            if (cc >= N) continue;
            float badd = cbias ? cbias[cc] : 0.f;
#pragma unroll
            for (int i = 0; i < 4; ++i) {
                int r = rm + i;
                if (r < M) C[(size_t)r * ldc + cc] = acc[m][n][i] + badd;
            }
        }
    }
}

// ----------------------------- fp32 gemm (small K only) -----------------------------

__global__ __launch_bounds__(256) void gemm64(const float* __restrict__ A, const float* __restrict__ B,
                                              float* __restrict__ C,
                                              int M, int N, int K, int lda, int ldb, int ldc,
                                              const float* __restrict__ bias, int relu) {
    __shared__ float As[16][65];
    __shared__ float Bs[16][65];
    int tid = threadIdx.x;
    int trow = tid / 16, tcol = tid % 16;
    int row0 = blockIdx.y * 64 + trow * 4;
    int col0 = blockIdx.x * 64 + tcol * 4;
    float acc[4][4] = {};
    int am = tid >> 2;
    int ak = (tid & 3) * 4;
    int bk = tid >> 4;
    int bn = (tid & 15) * 4;
    for (int k0 = 0; k0 < K; k0 += 16) {
        int gm = blockIdx.y * 64 + am;
#pragma unroll
        for (int u = 0; u < 4; ++u) {
            int gk = k0 + ak + u;
            As[ak + u][am] = (gm < M && gk < K) ? A[(size_t)gm * lda + gk] : 0.f;
        }
        int gbk = k0 + bk;
#pragma unroll
        for (int u = 0; u < 4; ++u) {
            int gn = blockIdx.x * 64 + bn + u;
            Bs[bk][bn + u] = (gbk < K && gn < N) ? B[(size_t)gbk * ldb + gn] : 0.f;
        }
        __syncthreads();
#pragma unroll
        for (int kk = 0; kk < 16; ++kk) {
            float a[4], b[4];
#pragma unroll
            for (int i = 0; i < 4; ++i) a[i] = As[kk][trow * 4 + i];
#pragma unroll
            for (int j = 0; j < 4; ++j) b[j] = Bs[kk][tcol * 4 + j];
#pragma unroll
            for (int i = 0; i < 4; ++i)
#pragma unroll
                for (int j = 0; j < 4; ++j) acc[i][j] += a[i] * b[j];
        }
        __syncthreads();
    }
#pragma unroll
    for (int i = 0; i < 4; ++i) {
        int r = row0 + i;
        if (r >= M) continue;
#pragma unroll
        for (int j = 0; j < 4; ++j) {
            int c = col0 + j;
            if (c < N) {
                float v = acc[i][j] + (bias ? bias[c] : 0.f);
                if (relu) v = fmaxf(v, 0.f);
                C[(size_t)r * ldc + c] = v;
            }
        }
    }
}

// ----------------------------- GCN glue -----------------------------

__global__ void scale_split_k(const float* __restrict__ xw, const float* __restrict__ dinv,
                              u16* __restrict__ zhT, u16* __restrict__ zlT, int M, int ldz) {
    __shared__ float t[32][33];
    int i0 = blockIdx.x * 32, f0 = blockIdx.y * 32;
#pragma unroll
    for (int it = 0; it < 4; ++it) {
        int r = it * 8 + (threadIdx.x >> 5);
        int c = threadIdx.x & 31;
        int i = i0 + r;
        t[r][c] = (i < M) ? dinv[i] * xw[(size_t)i * 128 + f0 + c] : 0.f;
    }
    __syncthreads();
#pragma unroll
    for (int it = 0; it < 4; ++it) {
        int r = it * 8 + (threadIdx.x >> 5);
        int c = threadIdx.x & 31;
        int f = f0 + r, i = i0 + c;
        float v = t[c][r];
        u16 h = f2b(v);
        zhT[(size_t)f * ldz + i] = h;
        zlT[(size_t)f * ldz + i] = f2b(v - b2f(h));
    }
}

__global__ void reduce_gcn_post_k(const float* __restrict__ part, int Z, int Mp,
                                  const float* __restrict__ xw, const float* __restrict__ dinv,
                                  const float* __restrict__ bias, float* __restrict__ y, int relu) {
    int i = blockIdx.x, f = threadIdx.x;
    size_t idx = (size_t)i * 128 + f;
    float s = 0.f;
    for (int z = 0; z < Z; ++z) s += part[(size_t)z * Mp * 128 + idx];
    float di = dinv[i];
    float v = di * s + di * di * xw[idx] + bias[f];
    y[idx] = relu ? fmaxf(v, 0.f) : v;
}

// ----------------------------- pooling -----------------------------

__global__ void score_k(const float* __restrict__ x, const float* __restrict__ pw,
                        float* __restrict__ score) {
    int i = blockIdx.x;
    __shared__ float red[128], red2[128];
    float p = pw[threadIdx.x];
    red[threadIdx.x]  = x[(size_t)i * 128 + threadIdx.x] * p;
    red2[threadIdx.x] = p * p;
    __syncthreads();
    for (int s = 64; s > 0; s >>= 1) {
        if (threadIdx.x < s) { red[threadIdx.x] += red[threadIdx.x + s]; red2[threadIdx.x] += red2[threadIdx.x + s]; }
        __syncthreads();
    }
    if (threadIdx.x == 0) score[i] = tanhf(red[0] / sqrtf(red2[0]));
}

__global__ __launch_bounds__(256) void rank_partial_k(const float* __restrict__ score, int n,
                                                      int* __restrict__ rankpart) {
    __shared__ float s_sh[512];
    int i = blockIdx.x * 256 + threadIdx.x;
    int jbase = blockIdx.y * 512;
    float si = (i < n) ? score[i] : -3.0f;
    for (int t = threadIdx.x; t < 512; t += 256) {
        int j = jbase + t;
        s_sh[t] = (j < n) ? score[j] : -3.0f;
    }
    __syncthreads();
    int cnt = 0;
#pragma unroll 16
    for (int t = 0; t < 512; ++t) {
        float sj = s_sh[t];
        cnt += (sj > si) || (sj == si && (jbase + t) < i);
    }
    if (i < n) rankpart[blockIdx.y * n + i] = cnt;
}

__global__ void scatter_topk_k(const float* __restrict__ score, const int* __restrict__ rankpart,
                               int nsl, int n, int k, int* __restrict__ perm, float* __restrict__ sc) {
    int i = blockIdx.x * 256 + threadIdx.x;
    if (i >= n) return;
    int r = 0;
    for (int s = 0; s < nsl; ++s) r += rankpart[s * n + i];
    if (r < k) { perm[r] = i; sc[r] = score[i]; }
}

__global__ void pool_x_k(float* __restrict__ xo, const float* __restrict__ xi,
                         const int* __restrict__ perm, const float* __restrict__ sc) {
    int a = blockIdx.x, f = threadIdx.x;
    xo[(size_t)a * 128 + f] = xi[(size_t)perm[a] * 128 + f] * sc[a];
}

__global__ void gather2_b_k(const u16* __restrict__ src0, const u16* __restrict__ src1,
                            int ldsrc, const int* __restrict__ perm,
                            u16* __restrict__ dst0, u16* __restrict__ dst1, int width) {
    const u16* src = blockIdx.y ? src1 : src0;
    u16* dst = blockIdx.y ? dst1 : dst0;
    int row = blockIdx.x;
    int p = perm[row];
    const uint4* s4 = (const uint4*)(src + (size_t)p * ldsrc);
    uint4* d4 = (uint4*)(dst + (size_t)row * width);
    int n8 = width >> 3;
    for (int j = threadIdx.x; j < n8; j += 256) d4[j] = s4[j];
    __syncthreads();
    if (threadIdx.x == 0) dst[(size_t)row * width + p] = 0x3F80;  // 1.0 bf16
}

__global__ void reduce_pool_k(const float* __restrict__ part, int Z, int k, int Mp, u16* __restrict__ out) {
    int row = blockIdx.x;
    for (int j = threadIdx.x; j < Mp; j += 256) {
        float s = 0.f;
        if (row < k && j < k) {
            for (int z = 0; z < Z; ++z) s += part[(size_t)z * Mp * Mp + (size_t)row * Mp + j];
            if (j == row) s = 0.f;
        }
        out[(size_t)row * Mp + j] = f2b(s);
    }
}

__global__ void scatter_add_k(float* __restrict__ xdst, const int* __restrict__ perm,
                              const float* __restrict__ xsrc) {
    int a = blockIdx.x, f = threadIdx.x;
    xdst[(size_t)perm[a] * 128 + f] += xsrc[(size_t)a * 128 + f];
}

// ----------------------------- head -----------------------------

__global__ void split_head_k(const float* __restrict__ x, u16* __restrict__ Ah, u16* __restrict__ Al) {
    int i = blockIdx.x, f = threadIdx.x;
    size_t idx = (size_t)i * 128 + f;
    float v = x[idx];
    u16 h = f2b(v);
    Ah[idx] = h;
    Al[idx] = f2b(v - b2f(h));
}

__global__ void convW3T_k(const float* __restrict__ W3, u16* __restrict__ W3T, int Nc, int Ncp) {
    __shared__ float t[64][65];
    int k0 = blockIdx.y * 64, n0 = blockIdx.x * 64;
    for (int e = threadIdx.x; e < 4096; e += 256) {
        int r = e >> 6, c = e & 63;
        t[r][c] = (k0 + r < 128 && n0 + c < Nc) ? W3[(size_t)(k0 + r) * Nc + n0 + c] : 0.f;
    }
    __syncthreads();
    for (int e = threadIdx.x; e < 4096; e += 256) {
        int r = e >> 6, c = e & 63;
        int nn = n0 + r, kk = k0 + c;
        if (nn < Ncp) W3T[(size_t)nn * 128 + kk] = f2b(t[c][r]);
    }
}

// register-resident log-softmax over C=6890 columns, one row per block.
__global__ __launch_bounds__(256) void logsoftmax_k(float* __restrict__ out) {
    const int C = 6890;
    const int CPT = 27;
    int row = blockIdx.x;
    float* rowp = out + (size_t)row * C;
    __shared__ float red[256];

    float v[CPT];
    float mx = -1e30f;
#pragma unroll
    for (int u = 0; u < CPT; ++u) {
        int c = threadIdx.x + u * 256;
        v[u] = (c < C) ? rowp[c] : -1e30f;
        mx = fmaxf(mx, v[u]);
    }
    red[threadIdx.x] = mx; __syncthreads();
    for (int s = 128; s > 0; s >>= 1) {
        if (threadIdx.x < s) red[threadIdx.x] = fmaxf(red[threadIdx.x], red[threadIdx.x + s]);
        __syncthreads();
    }
    float m = red[0];
    __syncthreads();

    float sum = 0.f;
#pragma unroll
    for (int u = 0; u < CPT; ++u) sum += __expf(v[u] - m);
    red[threadIdx.x] = sum; __syncthreads();
    for (int s = 128; s > 0; s >>= 1) {
        if (threadIdx.x < s) red[threadIdx.x] += red[threadIdx.x + s];
        __syncthreads();
    }
    float ls = m + logf(red[0]);

#pragma unroll
    for (int u = 0; u < CPT; ++u) {
        int c = threadIdx.x + u * 256;
        if (c < C) rowp[c] = v[u] - ls;
    }
}

// ----------------------------- entry -----------------------------

extern "C" void kernel_launch(void* const* d_in, const int* in_sizes, int n_in,
                              void* d_out, int out_size, void* d_ws, size_t ws_size,
                              hipStream_t stream) {
    const int N0 = 5000, K1 = 2000, K2 = 1000, K3 = 500, E = 80000, OUTC = 6890;
    const int Np0 = 5120, Kp1 = 2048, Kp2 = 1024, Kp3 = 512, OUTCP = 6912;
    (void)in_sizes; (void)n_in; (void)out_size; (void)ws_size;

    const float* pos = (const float*)d_in[0];
    const int*   ei  = (const int*)d_in[1];
    const float* Wd0 = (const float*)d_in[2];  const float* bd0 = (const float*)d_in[3];
    const float* Wd1 = (const float*)d_in[4];  const float* bd1 = (const float*)d_in[5];
    const float* Wd2 = (const float*)d_in[6];  const float* bd2 = (const float*)d_in[7];
    const float* Wd3 = (const float*)d_in[8];  const float* bd3 = (const float*)d_in[9];
    const float* pw0 = (const float*)d_in[10];
    const float* pw1 = (const float*)d_in[11];
    const float* pw2 = (const float*)d_in[12];
    const float* Wu0 = (const float*)d_in[13]; const float* bu0 = (const float*)d_in[14];
    const float* Wu1 = (const float*)d_in[15]; const float* bu1 = (const float*)d_in[16];
    const float* Wu2 = (const float*)d_in[17]; const float* bu2 = (const float*)d_in[18];
    const float* W1  = (const float*)d_in[19]; const float* b1  = (const float*)d_in[20];
    const float* W2  = (const float*)d_in[21]; const float* b2  = (const float*)d_in[22];
    const float* W3  = (const float*)d_in[23]; const float* b3  = (const float*)d_in[24];

    float* w = (float*)d_ws;
    size_t off = 0;
    auto alloc = [&](size_t nel) { float* p = w + off; off += nel; return p; };

    // pool region (26.22M floats = 5120^2): adj0 fp32 transiently; then
    //   partials [0,13M) | G [13M,18.25M) | HT [18.25M,23.5M)
    //   A2i (sparse pool-0, 4.2M ints) aliases partials; zhT/zlT overlap G (GCN phase);
    //   Ah/Al overlap partials (head phase only)
    float* pool = alloc(26220000);
    float* adj0 = pool;
    float* partials = pool;
    u16* G   = (u16*)(pool + 13000000);
    u16* HT  = (u16*)(pool + 18250000);
    u16* zhT = (u16*)(pool + 13000000);
    u16* zlT = (u16*)(pool + 13400000);
    u16* Ah  = (u16*)(pool);
    u16* Al  = (u16*)(pool + 400000);

    u16* adj0b  = (u16*)alloc(13107200);     // 5120 x 5120
    u16* adj1b  = (u16*)alloc(2097152);      // 2048 x 2048
    u16* adj1bT = (u16*)alloc(2097152);
    u16* adj2b  = (u16*)alloc(524288);       // 1024 x 1024
    u16* adj2bT = (u16*)alloc(524288);
    u16* adj3b  = (u16*)alloc(131072);       // 512 x 512
    u16* W3T    = (u16*)alloc(442368);       // 6912 x 128

    float* x0 = alloc((size_t)N0 * 128);
    float* x1 = alloc((size_t)K1 * 128);
    float* x2 = alloc((size_t)K2 * 128);
    float* xa = alloc((size_t)N0 * 128);
    float* xb = alloc((size_t)N0 * 128);
    float* xw = alloc((size_t)N0 * 128);
    float* dinv0 = alloc(N0); float* dinv1 = alloc(K1); float* dinv2 = alloc(K2); float* dinv3 = alloc(K3);
    float* scorev = alloc(N0);
    float* scv    = alloc(K1);
    int* perm0 = (int*)alloc(K1);
    int* perm1 = (int*)alloc(K2);
    int* perm2 = (int*)alloc(K3);
    int* rankpart = (int*)alloc(50048);      // up to 10 slices x 5000
    int* rowcnt = (int*)alloc(5120);
    int* rowptr = (int*)alloc(5120);
    int* fillc  = (int*)alloc(5120);
    int* colsb  = (int*)alloc(80000);
    int* invb   = (int*)alloc(5120);

    auto launch_mm = [&](int SA, int SB, const u16* A0, const u16* A1, const u16* B0, const u16* B1,
                         float* Cc, const float* cbias, int M, int N, int Kpad,
                         int lda, int ldb, int ldc, size_t cstride, int Z) -> int {
        int kPerZ = CDIV(Kpad, Z * 32) * 32;
        int gz = CDIV(Kpad, kPerZ);
        dim3 g(CDIV(N, 128), CDIV(M, 128), gz);
        if (SA)      mm_nt<1, 0><<<g, 256, 0, stream>>>(A0, A1, B0, B1, Cc, cbias, M, N, lda, ldb, ldc, kPerZ, Kpad, cstride);
        else if (SB) mm_nt<0, 1><<<g, 256, 0, stream>>>(A0, A1, B0, B1, Cc, cbias, M, N, lda, ldb, ldc, kPerZ, Kpad, cstride);
        else         mm_nt<0, 0><<<g, 256, 0, stream>>>(A0, A1, B0, B1, Cc, cbias, M, N, lda, ldb, ldc, kPerZ, Kpad, cstride);
        return gz;
    };

    auto run_gcn = [&](const u16* adjb, int n, int Np,
                       const float* x, int kin, const float* W, const float* bias,
                       const float* dinv, int relu, float* y, int Z) {
        gemm64<<<dim3(2, CDIV(n, 64)), 256, 0, stream>>>(x, W, xw, n, 128, kin, kin, 128, 128, nullptr, 0);
        scale_split_k<<<dim3(Np / 32, 4), 256, 0, stream>>>(xw, dinv, zhT, zlT, n, Np);
        int gz = launch_mm(0, 1, adjb, nullptr, zhT, zlT, partials, nullptr,
                           Np, 128, Np, Np, Np, 128, (size_t)Np * 128, Z);
        reduce_gcn_post_k<<<n, 128, 0, stream>>>(partials, gz, Np, xw, dinv, bias, y, relu);
    };

    auto run_pool = [&](const float* x, int n, int Np, int kNew, int KpNew, const float* pw,
                        const u16* srcb, const u16* srcbT, u16* adjNew, int* perm, int Z) {
        score_k<<<n, 128, 0, stream>>>(x, pw, scorev);
        int nsl = CDIV(n, 512);
        rank_partial_k<<<dim3(CDIV(n, 256), nsl), 256, 0, stream>>>(scorev, n, rankpart);
        scatter_topk_k<<<CDIV(n, 256), 256, 0, stream>>>(scorev, rankpart, nsl, n, kNew, perm, scv);
        pool_x_k<<<kNew, 128, 0, stream>>>(xa, x, perm, scv);
        gather2_b_k<<<dim3(kNew, 2), 256, 0, stream>>>(srcb, srcbT, Np, perm, G, HT, Np);
        int gz = launch_mm(0, 0, G, nullptr, HT, nullptr, partials, nullptr,
                           KpNew, KpNew, Np, Np, Np, KpNew, (size_t)KpNew * KpNew, Z);
        reduce_pool_k<<<KpNew, 256, 0, stream>>>(partials, gz, kNew, KpNew, adjNew);
    };

    // ---- build adjacency (padded fp32) -> bf16, dinv0; CSR of non-self edges ----
    hipMemsetAsync(adj0, 0, (size_t)Np0 * Np0 * sizeof(float), stream);
    hipMemsetAsync(rowcnt, 0, N0 * sizeof(int), stream);
    hipMemsetAsync(fillc, 0, N0 * sizeof(int), stream);
    build_adj_k<<<CDIV(E, 256), 256, 0, stream>>>(ei, adj0, E, Np0);
    csr_cnt_k<<<CDIV(E, 256), 256, 0, stream>>>(ei, E, rowcnt);
    prefix_k<<<1, 1024, 0, stream>>>(rowcnt, rowptr, N0);
    csr_fill_k<<<CDIV(E, 256), 256, 0, stream>>>(ei, E, rowptr, fillc, colsb);
    convS_k<<<CDIV((size_t)Np0 * Np0 / 4, 256), 256, 0, stream>>>(adj0, adj0b, (size_t)Np0 * Np0 / 4);
    rowsum_dinv_b_k<<<N0, 256, 0, stream>>>(adj0b, Np0, Np0, dinv0);

    // ---- initial GCN ----
    run_gcn(adj0b, N0, Np0, pos, 3, Wd0, bd0, dinv0, 1, x0, 10);

    // ---- down level 0: 5000 -> 2000 (SPARSE pool: exact integer SpGEMM) ----
    score_k<<<N0, 128, 0, stream>>>(x0, pw0, scorev);
    {
        int nsl = CDIV(N0, 512);
        rank_partial_k<<<dim3(CDIV(N0, 256), nsl), 256, 0, stream>>>(scorev, N0, rankpart);
        scatter_topk_k<<<CDIV(N0, 256), 256, 0, stream>>>(scorev, rankpart, nsl, N0, K1, perm0, scv);
    }
    pool_x_k<<<K1, 128, 0, stream>>>(xa, x0, perm0, scv);
    hipMemsetAsync(invb, 0xFF, N0 * sizeof(int), stream);
    inv_k<<<CDIV(K1, 256), 256, 0, stream>>>(perm0, K1, invb);
    int* A2i = (int*)partials;
    hipMemsetAsync(A2i, 0, (size_t)Kp1 * Kp1 * sizeof(int), stream);
    spgemm_k<<<K1, 256, 0, stream>>>(perm0, rowptr, colsb, invb, A2i, Kp1);
    conv_spg_k<<<Kp1, 256, 0, stream>>>(A2i, K1, Kp1, adj1b);

    transpose_b_k<<<dim3(Kp1 / 64, Kp1 / 64), 256, 0, stream>>>(adj1b, adj1bT, Kp1);
    rowsum_dinv_b_k<<<K1, 256, 0, stream>>>(adj1b, Kp1, Kp1, dinv1);
    run_gcn(adj1b, K1, Kp1, xa, 128, Wd1, bd1, dinv1, 1, x1, 16);

    // ---- down level 1: 2000 -> 1000 (dense) ----
    run_pool(x1, K1, Kp1, K2, Kp2, pw1, adj1b, adj1bT, adj2b, perm1, 8);
    transpose_b_k<<<dim3(Kp2 / 64, Kp2 / 64), 256, 0, stream>>>(adj2b, adj2bT, Kp2);
    rowsum_dinv_b_k<<<K2, 256, 0, stream>>>(adj2b, Kp2, Kp2, dinv2);
    run_gcn(adj2b, K2, Kp2, xa, 128, Wd2, bd2, dinv2, 1, x2, 16);

    // ---- down level 2: 1000 -> 500 (dense) ----
    run_pool(x2, K2, Kp2, K3, Kp3, pw2, adj2b, adj2bT, adj3b, perm2, 8);
    rowsum_dinv_b_k<<<K3, 256, 0, stream>>>(adj3b, Kp3, Kp3, dinv3);
    run_gcn(adj3b, K3, Kp3, xa, 128, Wd3, bd3, dinv3, 1, xb, 8);           // xb: 500x128

    // ---- up i=0 (j=2) ----
    hipMemcpyAsync(xa, x2, (size_t)K2 * 128 * sizeof(float), hipMemcpyDeviceToDevice, stream);
    scatter_add_k<<<K3, 128, 0, stream>>>(xa, perm2, xb);
    run_gcn(adj2b, K2, Kp2, xa, 128, Wu0, bu0, dinv2, 1, xb, 16);          // xb: 1000x128

    // ---- up i=1 (j=1) ----
    hipMemcpyAsync(xa, x1, (size_t)K1 * 128 * sizeof(float), hipMemcpyDeviceToDevice, stream);
    scatter_add_k<<<K2, 128, 0, stream>>>(xa, perm1, xb);
    run_gcn(adj1b, K1, Kp1, xa, 128, Wu1, bu1, dinv1, 1, xb, 16);          // xb: 2000x128

    // ---- up i=2 (j=0), no relu ----
    hipMemcpyAsync(xa, x0, (size_t)N0 * 128 * sizeof(float), hipMemcpyDeviceToDevice, stream);
    scatter_add_k<<<K1, 128, 0, stream>>>(xa, perm0, xb);
    run_gcn(adj0b, N0, Np0, xa, 128, Wu2, bu2, dinv0, 0, xb, 10);          // xb: 5000x128

    // ---- MLP head (bias+relu fused in gemm64 epilogue) ----
    gemm64<<<dim3(2, CDIV(N0, 64)), 256, 0, stream>>>(xb, W1, xa, N0, 128, 128, 128, 128, 128, b1, 1);
    gemm64<<<dim3(2, CDIV(N0, 64)), 256, 0, stream>>>(xa, W2, xw, N0, 128, 128, 128, 128, 128, b2, 0);

    split_head_k<<<N0, 128, 0, stream>>>(xw, Ah, Al);
    convW3T_k<<<dim3(OUTCP / 64, 2), 256, 0, stream>>>(W3, W3T, OUTC, OUTCP);

    float* outp = (float*)d_out;
    launch_mm(1, 0, Ah, Al, W3T, nullptr, outp, b3, N0, OUTC, 128, 128, 128, OUTC, 0, 1);
    logsoftmax_k<<<N0, 256, 0, stream>>>(outp);
}

// Round 12
// 725.891 us; speedup vs baseline: 1.2849x; 1.1257x over previous
//
#include <hip/hip_runtime.h>
#include <cmath>

#define CDIV(a,b) (((a)+(b)-1)/(b))

using u16 = unsigned short;
using short8 = __attribute__((ext_vector_type(8))) short;
using f32x4 = __attribute__((ext_vector_type(4))) float;

__device__ __forceinline__ u16 f2b(float v) {
    union { float f; unsigned u; } x; x.f = v;
    unsigned r = x.u + 0x7fffu + ((x.u >> 16) & 1u);
    return (u16)(r >> 16);
}
__device__ __forceinline__ float b2f(u16 h) {
    union { unsigned u; float f; } x; x.u = ((unsigned)h) << 16;
    return x.f;
}

#if defined(__has_builtin)
#if __has_builtin(__builtin_amdgcn_global_load_lds)
#define HAS_GLL 1
#endif
#endif
#ifndef HAS_GLL
#define HAS_GLL 0
#endif

__device__ __forceinline__ void g2l(const u16* g, uint4* l) {
#if HAS_GLL
    __builtin_amdgcn_global_load_lds((const __attribute__((address_space(1))) void*)g,
                                     (__attribute__((address_space(3))) void*)l, 16, 0, 0);
#else
    *l = *(const uint4*)g;
#endif
}

// ----------------------------- CSR build (ALL edges, self included) ----------------

__global__ void csr_cnt_k(const int* __restrict__ ei, int E, int* __restrict__ rowcnt) {
    int e = blockIdx.x * 256 + threadIdx.x;
    if (e < E) atomicAdd(&rowcnt[ei[e]], 1);
}

// single-block Hillis-Steele scan of n<=5120 ints -> exclusive rowptr[n+1]
__global__ __launch_bounds__(1024) void prefix_k(const int* __restrict__ cnt, int* __restrict__ ptr, int n) {
    __shared__ int buf[5120];
    for (int i = threadIdx.x; i < 5120; i += 1024) buf[i] = (i < n) ? cnt[i] : 0;
    __syncthreads();
    for (int d = 1; d < 5120; d <<= 1) {
        int vals[5];
#pragma unroll
        for (int c = 0; c < 5; ++c) {
            int i = threadIdx.x + c * 1024;
            vals[c] = (i >= d) ? buf[i - d] : 0;
        }
        __syncthreads();
#pragma unroll
        for (int c = 0; c < 5; ++c) {
            int i = threadIdx.x + c * 1024;
            buf[i] += vals[c];
        }
        __syncthreads();
    }
    for (int i = threadIdx.x; i <= n; i += 1024) ptr[i] = (i == 0) ? 0 : buf[i - 1];
}

__global__ void csr_fill_k(const int* __restrict__ ei, int E, const int* __restrict__ rowptr,
                           int* __restrict__ fill, int* __restrict__ cols) {
    int e = blockIdx.x * 256 + threadIdx.x;
    if (e < E) {
        int u = ei[e];
        int p = rowptr[u] + atomicAdd(&fill[u], 1);
        cols[p] = ei[E + e];
    }
}

// per-row insertion sort (deg ~16) -> deterministic iteration order
__global__ void sortrows_k(const int* __restrict__ rowptr, int* __restrict__ cols, int n) {
    int i = blockIdx.x * 256 + threadIdx.x;
    if (i >= n) return;
    int s = rowptr[i], e = rowptr[i + 1];
    for (int p = s + 1; p < e; ++p) {
        int v = cols[p];
        int q = p - 1;
        while (q >= s && cols[q] > v) { cols[q + 1] = cols[q]; --q; }
        cols[q + 1] = v;
    }
}

__global__ void dinv_from_cnt_k(const int* __restrict__ cnt, float* __restrict__ dinv, int n) {
    int i = blockIdx.x * 256 + threadIdx.x;
    if (i < n) dinv[i] = rsqrtf((float)cnt[i] + 1.0f);
}

// fused sparse GCN aggregation + post (exact fp32):
// y[i][f] = act(di * sum_{edges(i,d)} dinv[d]*xw[d][f] + di^2*xw[i][f] + b[f])
__global__ __launch_bounds__(128) void spmm_gcn_k(const int* __restrict__ rowptr, const int* __restrict__ cols,
                                                  const float* __restrict__ dinv, const float* __restrict__ xw,
                                                  const float* __restrict__ bias, float* __restrict__ y, int relu) {
    int i = blockIdx.x, f = threadIdx.x;
    int s = rowptr[i], e = rowptr[i + 1];
    float acc = 0.f;
    for (int p = s; p < e; ++p) {
        int d = cols[p];
        acc += dinv[d] * xw[(size_t)d * 128 + f];
    }
    float di = dinv[i];
    float v = di * acc + di * di * xw[(size_t)i * 128 + f] + bias[f];
    y[(size_t)i * 128 + f] = relu ? fmaxf(v, 0.f) : v;
}

// ----------------------------- sparse pool-0 SpGEMM (exact integers) --------------

__global__ void inv_k(const int* __restrict__ perm, int k, int* __restrict__ inv) {
    int r = blockIdx.x * 256 + threadIdx.x;
    if (r < k) inv[perm[r]] = r;
}

// A2[a][b] += pairs (pa->k!=pa, k->pb!=k) + 2*(pa->pb!=pa); CSR-all with inline self-skip.
__global__ __launch_bounds__(256) void spgemm_k(const int* __restrict__ perm, const int* __restrict__ rowptr,
                                                const int* __restrict__ cols, const int* __restrict__ inv,
                                                int* __restrict__ A2, int ldo) {
    __shared__ int nb[256];
    __shared__ int degs;
    int a = blockIdx.x;
    int pa = perm[a];
    int s = rowptr[pa], epos = rowptr[pa + 1];
    int d = epos - s;
    if (threadIdx.x == 0) degs = d > 256 ? 256 : d;
    if (threadIdx.x < d && threadIdx.x < 256) nb[threadIdx.x] = cols[s + threadIdx.x];
    __syncthreads();
    int* rowA2 = A2 + (size_t)a * ldo;
    for (int p = s + threadIdx.x; p < epos; p += 256) {
        int c = cols[p];
        if (c != pa) {
            int b = inv[c];
            if (b >= 0) atomicAdd(&rowA2[b], 2);
        }
    }
    int dd = degs;
    for (int j = 0; j < dd; ++j) {
        int kk = nb[j];
        if (kk == pa) continue;
        int s2 = rowptr[kk], e2 = rowptr[kk + 1];
        for (int p = s2 + threadIdx.x; p < e2; p += 256) {
            int pb = cols[p];
            if (pb != kk) {
                int b = inv[pb];
                if (b >= 0) atomicAdd(&rowA2[b], 1);
            }
        }
    }
}

// int counts -> bf16 padded adj, diag + pad zeroed
__global__ void conv_spg_k(const int* __restrict__ A2, int kNew, int Mp, u16* __restrict__ out) {
    int r = blockIdx.x;
    for (int j = threadIdx.x; j < Mp; j += 256) {
        int v = 0;
        if (r < kNew && j < kNew && j != r) v = A2[(size_t)r * Mp + j];
        out[(size_t)r * Mp + j] = f2b((float)v);
    }
}

// ----------------------------- dense helpers -----------------------------

__global__ void rowsum_dinv_b_k(const u16* __restrict__ adjb, int ld, int n, float* __restrict__ dinv) {
    int i = blockIdx.x;
    __shared__ float red[256];
    const u16* row = adjb + (size_t)i * ld;
    float s = 0.f;
    for (int j = threadIdx.x; j < n; j += 256) s += b2f(row[j]);
    red[threadIdx.x] = s; __syncthreads();
    for (int w = 128; w > 0; w >>= 1) {
        if (threadIdx.x < w) red[threadIdx.x] += red[threadIdx.x + w];
        __syncthreads();
    }
    if (threadIdx.x == 0) dinv[i] = rsqrtf(red[0] + 1.0f);
}

__global__ void transpose_b_k(const u16* __restrict__ in, u16* __restrict__ out, int n) {
    __shared__ u16 t[64][65];
    int i0 = blockIdx.y * 64, j0 = blockIdx.x * 64;
    for (int e = threadIdx.x; e < 4096; e += 256) {
        int r = e >> 6, c = e & 63;
        t[r][c] = in[(size_t)(i0 + r) * n + j0 + c];
    }
    __syncthreads();
    for (int e = threadIdx.x; e < 4096; e += 256) {
        int r = e >> 6, c = e & 63;
        out[(size_t)(j0 + r) * n + i0 + c] = t[c][r];
    }
}

// --------- MFMA GEMM, NT form, padded (no staging guards), gload_lds, BK=32 ---------

template<int SA, int SB>
__global__ __launch_bounds__(256) void mm_nt(const u16* __restrict__ A0, const u16* __restrict__ A1,
                                             const u16* __restrict__ B0, const u16* __restrict__ B1,
                                             float* __restrict__ C, const float* __restrict__ cbias,
                                             int M, int N, int lda, int ldb, int ldc,
                                             int kPerZ, int Kpad, size_t cstride) {
    __shared__ uint4 lds_t[(2 + SA + SB) * 512];
    uint4* Ab  = lds_t;
    uint4* A1b = lds_t + (SA ? 512 : 0);
    uint4* Bb  = lds_t + (1 + SA) * 512;
    uint4* B1b = Bb + (SB ? 512 : 0);

    int tid = threadIdx.x;

    int nx = gridDim.x, nxy = nx * gridDim.y;
    int bx = blockIdx.x, by = blockIdx.y;
    if ((nxy & 7) == 0) {
        int flat = by * nx + bx;
        int nf = (flat & 7) * (nxy >> 3) + (flat >> 3);
        bx = nf % nx; by = nf / nx;
    }
    int row0 = by * 128, col0 = bx * 128;

    int kbeg = blockIdx.z * kPerZ;
    int kend = min(kbeg + kPerZ, Kpad);
    C += (size_t)blockIdx.z * cstride;

    int wave = tid >> 6, lane = tid & 63;
    int wr = (wave >> 1) * 64, wc = (wave & 1) * 64;
    int lrow = lane & 15, kg = lane >> 4;

    int tS0 = tid, tS1 = tid + 256;
    int R0 = ((tS0 >> 6) << 4) | (tS0 & 15), kc0 = (tS0 >> 4) & 3;
    int R1 = ((tS1 >> 6) << 4) | (tS1 & 15), kc1 = (tS1 >> 4) & 3;

    const u16* aP0 = A0 + (size_t)(row0 + R0) * lda + kbeg + kc0 * 8;
    const u16* aP1 = A0 + (size_t)(row0 + R1) * lda + kbeg + kc1 * 8;
    const u16* bP0 = B0 + (size_t)(col0 + R0) * ldb + kbeg + kc0 * 8;
    const u16* bP1 = B0 + (size_t)(col0 + R1) * ldb + kbeg + kc1 * 8;
    const u16* a1P0 = SA ? (A1 + (size_t)(row0 + R0) * lda + kbeg + kc0 * 8) : nullptr;
    const u16* a1P1 = SA ? (A1 + (size_t)(row0 + R1) * lda + kbeg + kc1 * 8) : nullptr;
    const u16* b1P0 = SB ? (B1 + (size_t)(col0 + R0) * ldb + kbeg + kc0 * 8) : nullptr;
    const u16* b1P1 = SB ? (B1 + (size_t)(col0 + R1) * ldb + kbeg + kc1 * 8) : nullptr;

    f32x4 acc[4][4] = {};

    for (int k0 = kbeg; k0 < kend; k0 += 32) {
        __syncthreads();
        g2l(aP0, Ab + tS0);
        g2l(aP1, Ab + tS1);
        if constexpr (SA) { g2l(a1P0, A1b + tS0); g2l(a1P1, A1b + tS1); }
        g2l(bP0, Bb + tS0);
        g2l(bP1, Bb + tS1);
        if constexpr (SB) { g2l(b1P0, B1b + tS0); g2l(b1P1, B1b + tS1); }
        __syncthreads();

        const short8* Ap  = (const short8*)Ab;
        const short8* A1p = (const short8*)A1b;
        const short8* Bp  = (const short8*)Bb;
        const short8* B1p = (const short8*)B1b;

        short8 a[4], a1[4], b[4], b1[4];
#pragma unroll
        for (int m = 0; m < 4; ++m) {
            int idx = (((wr >> 4) + m) << 6) | (kg << 4) | lrow;
            a[m] = Ap[idx];
            if constexpr (SA) a1[m] = A1p[idx];
        }
#pragma unroll
        for (int n = 0; n < 4; ++n) {
            int idx = (((wc >> 4) + n) << 6) | (kg << 4) | lrow;
            b[n] = Bp[idx];
            if constexpr (SB) b1[n] = B1p[idx];
        }
#pragma unroll
        for (int m = 0; m < 4; ++m)
#pragma unroll
            for (int n = 0; n < 4; ++n) {
                acc[m][n] = __builtin_amdgcn_mfma_f32_16x16x32_bf16(a[m], b[n], acc[m][n], 0, 0, 0);
                if constexpr (SA) acc[m][n] = __builtin_amdgcn_mfma_f32_16x16x32_bf16(a1[m], b[n], acc[m][n], 0, 0, 0);
                if constexpr (SB) acc[m][n] = __builtin_amdgcn_mfma_f32_16x16x32_bf16(a[m], b1[n], acc[m][n], 0, 0, 0);
            }

        aP0 += 32; aP1 += 32; bP0 += 32; bP1 += 32;
        if constexpr (SA) { a1P0 += 32; a1P1 += 32; }
        if constexpr (SB) { b1P0 += 32; b1P1 += 32; }
    }

#pragma unroll
    for (int m = 0; m < 4; ++m) {
        int rm = row0 + wr + m * 16 + kg * 4;
#pragma unroll
        for (int n = 0; n < 4; ++n) {
            int cc = col0 + wc + n * 16 + lrow;
            if (cc >= N) continue;
            float badd = cbias ? cbias[cc] : 0.f;
#pragma unroll
            for (int i = 0; i < 4; ++i) {
                int r = rm + i;
                if (r < M) C[(size_t)r * ldc + cc] = acc[m][n][i] + badd;
            }
        }
    }
}

// ----------------------------- fp32 gemm (small K only) -----------------------------

__global__ __launch_bounds__(256) void gemm64(const float* __restrict__ A, const float* __restrict__ B,
                                              float* __restrict__ C,
                                              int M, int N, int K, int lda, int ldb, int ldc,
                                              const float* __restrict__ bias, int relu) {
    __shared__ float As[16][65];
    __shared__ float Bs[16][65];
    int tid = threadIdx.x;
    int trow = tid / 16, tcol = tid % 16;
    int row0 = blockIdx.y * 64 + trow * 4;
    int col0 = blockIdx.x * 64 + tcol * 4;
    float acc[4][4] = {};
    int am = tid >> 2;
    int ak = (tid & 3) * 4;
    int bk = tid >> 4;
    int bn = (tid & 15) * 4;
    for (int k0 = 0; k0 < K; k0 += 16) {
        int gm = blockIdx.y * 64 + am;
#pragma unroll
        for (int u = 0; u < 4; ++u) {
            int gk = k0 + ak + u;
            As[ak + u][am] = (gm < M && gk < K) ? A[(size_t)gm * lda + gk] : 0.f;
        }
        int gbk = k0 + bk;
#pragma unroll
        for (int u = 0; u < 4; ++u) {
            int gn = blockIdx.x * 64 + bn + u;
            Bs[bk][bn + u] = (gbk < K && gn < N) ? B[(size_t)gbk * ldb + gn] : 0.f;
        }
        __syncthreads();
#pragma unroll
        for (int kk = 0; kk < 16; ++kk) {
            float a[4], b[4];
#pragma unroll
            for (int i = 0; i < 4; ++i) a[i] = As[kk][trow * 4 + i];
#pragma unroll
            for (int j = 0; j < 4; ++j) b[j] = Bs[kk][tcol * 4 + j];
#pragma unroll
            for (int i = 0; i < 4; ++i)
#pragma unroll
                for (int j = 0; j < 4; ++j) acc[i][j] += a[i] * b[j];
        }
        __syncthreads();
    }
#pragma unroll
    for (int i = 0; i < 4; ++i) {
        int r = row0 + i;
        if (r >= M) continue;
#pragma unroll
        for (int j = 0; j < 4; ++j) {
            int c = col0 + j;
            if (c < N) {
                float v = acc[i][j] + (bias ? bias[c] : 0.f);
                if (relu) v = fmaxf(v, 0.f);
                C[(size_t)r * ldc + c] = v;
            }
        }
    }
}

// ----------------------------- GCN glue (dense levels) -----------------------------

__global__ void scale_split_k(const float* __restrict__ xw, const float* __restrict__ dinv,
                              u16* __restrict__ zhT, u16* __restrict__ zlT, int M, int ldz) {
    __shared__ float t[32][33];
    int i0 = blockIdx.x * 32, f0 = blockIdx.y * 32;
#pragma unroll
    for (int it = 0; it < 4; ++it) {
        int r = it * 8 + (threadIdx.x >> 5);
        int c = threadIdx.x & 31;
        int i = i0 + r;
        t[r][c] = (i < M) ? dinv[i] * xw[(size_t)i * 128 + f0 + c] : 0.f;
    }
    __syncthreads();
#pragma unroll
    for (int it = 0; it < 4; ++it) {
        int r = it * 8 + (threadIdx.x >> 5);
        int c = threadIdx.x & 31;
        int f = f0 + r, i = i0 + c;
        float v = t[c][r];
        u16 h = f2b(v);
        zhT[(size_t)f * ldz + i] = h;
        zlT[(size_t)f * ldz + i] = f2b(v - b2f(h));
    }
}

__global__ void reduce_gcn_post_k(const float* __restrict__ part, int Z, int Mp,
                                  const float* __restrict__ xw, const float* __restrict__ dinv,
                                  const float* __restrict__ bias, float* __restrict__ y, int relu) {
    int i = blockIdx.x, f = threadIdx.x;
    size_t idx = (size_t)i * 128 + f;
    float s = 0.f;
    for (int z = 0; z < Z; ++z) s += part[(size_t)z * Mp * 128 + idx];
    float di = dinv[i];
    float v = di * s + di * di * xw[idx] + bias[f];
    y[idx] = relu ? fmaxf(v, 0.f) : v;
}

// ----------------------------- pooling -----------------------------

__global__ void score_k(const float* __restrict__ x, const float* __restrict__ pw,
                        float* __restrict__ score) {
    int i = blockIdx.x;
    __shared__ float red[128], red2[128];
    float p = pw[threadIdx.x];
    red[threadIdx.x]  = x[(size_t)i * 128 + threadIdx.x] * p;
    red2[threadIdx.x] = p * p;
    __syncthreads();
    for (int s = 64; s > 0; s >>= 1) {
        if (threadIdx.x < s) { red[threadIdx.x] += red[threadIdx.x + s]; red2[threadIdx.x] += red2[threadIdx.x + s]; }
        __syncthreads();
    }
    if (threadIdx.x == 0) score[i] = tanhf(red[0] / sqrtf(red2[0]));
}

__global__ __launch_bounds__(256) void rank_partial_k(const float* __restrict__ score, int n,
                                                      int* __restrict__ rankpart) {
    __shared__ float s_sh[512];
    int i = blockIdx.x * 256 + threadIdx.x;
    int jbase = blockIdx.y * 512;
    float si = (i < n) ? score[i] : -3.0f;
    for (int t = threadIdx.x; t < 512; t += 256) {
        int j = jbase + t;
        s_sh[t] = (j < n) ? score[j] : -3.0f;
    }
    __syncthreads();
    int cnt = 0;
#pragma unroll 16
    for (int t = 0; t < 512; ++t) {
        float sj = s_sh[t];
        cnt += (sj > si) || (sj == si && (jbase + t) < i);
    }
    if (i < n) rankpart[blockIdx.y * n + i] = cnt;
}

__global__ void scatter_topk_k(const float* __restrict__ score, const int* __restrict__ rankpart,
                               int nsl, int n, int k, int* __restrict__ perm, float* __restrict__ sc) {
    int i = blockIdx.x * 256 + threadIdx.x;
    if (i >= n) return;
    int r = 0;
    for (int s = 0; s < nsl; ++s) r += rankpart[s * n + i];
    if (r < k) { perm[r] = i; sc[r] = score[i]; }
}

__global__ void pool_x_k(float* __restrict__ xo, const float* __restrict__ xi,
                         const int* __restrict__ perm, const float* __restrict__ sc) {
    int a = blockIdx.x, f = threadIdx.x;
    xo[(size_t)a * 128 + f] = xi[(size_t)perm[a] * 128 + f] * sc[a];
}

__global__ void gather2_b_k(const u16* __restrict__ src0, const u16* __restrict__ src1,
                            int ldsrc, const int* __restrict__ perm,
                            u16* __restrict__ dst0, u16* __restrict__ dst1, int width) {
    const u16* src = blockIdx.y ? src1 : src0;
    u16* dst = blockIdx.y ? dst1 : dst0;
    int row = blockIdx.x;
    int p = perm[row];
    const uint4* s4 = (const uint4*)(src + (size_t)p * ldsrc);
    uint4* d4 = (uint4*)(dst + (size_t)row * width);
    int n8 = width >> 3;
    for (int j = threadIdx.x; j < n8; j += 256) d4[j] = s4[j];
    __syncthreads();
    if (threadIdx.x == 0) dst[(size_t)row * width + p] = 0x3F80;  // 1.0 bf16
}

__global__ void reduce_pool_k(const float* __restrict__ part, int Z, int k, int Mp, u16* __restrict__ out) {
    int row = blockIdx.x;
    for (int j = threadIdx.x; j < Mp; j += 256) {
        float s = 0.f;
        if (row < k && j < k) {
            for (int z = 0; z < Z; ++z) s += part[(size_t)z * Mp * Mp + (size_t)row * Mp + j];
            if (j == row) s = 0.f;
        }
        out[(size_t)row * Mp + j] = f2b(s);
    }
}

__global__ void scatter_add_k(float* __restrict__ xdst, const int* __restrict__ perm,
                              const float* __restrict__ xsrc) {
    int a = blockIdx.x, f = threadIdx.x;
    xdst[(size_t)perm[a] * 128 + f] += xsrc[(size_t)a * 128 + f];
}

// ----------------------------- head -----------------------------

__global__ void split_head_k(const float* __restrict__ x, u16* __restrict__ Ah, u16* __restrict__ Al) {
    int i = blockIdx.x, f = threadIdx.x;
    size_t idx = (size_t)i * 128 + f;
    float v = x[idx];
    u16 h = f2b(v);
    Ah[idx] = h;
    Al[idx] = f2b(v - b2f(h));
}

__global__ void convW3T_k(const float* __restrict__ W3, u16* __restrict__ W3T, int Nc, int Ncp) {
    __shared__ float t[64][65];
    int k0 = blockIdx.y * 64, n0 = blockIdx.x * 64;
    for (int e = threadIdx.x; e < 4096; e += 256) {
        int r = e >> 6, c = e & 63;
        t[r][c] = (k0 + r < 128 && n0 + c < Nc) ? W3[(size_t)(k0 + r) * Nc + n0 + c] : 0.f;
    }
    __syncthreads();
    for (int e = threadIdx.x; e < 4096; e += 256) {
        int r = e >> 6, c = e & 63;
        int nn = n0 + r, kk = k0 + c;
        if (nn < Ncp) W3T[(size_t)nn * 128 + kk] = f2b(t[c][r]);
    }
}

// register-resident log-softmax over C=6890 columns, one row per block.
__global__ __launch_bounds__(256) void logsoftmax_k(float* __restrict__ out) {
    const int C = 6890;
    const int CPT = 27;
    int row = blockIdx.x;
    float* rowp = out + (size_t)row * C;
    __shared__ float red[256];

    float v[CPT];
    float mx = -1e30f;
#pragma unroll
    for (int u = 0; u < CPT; ++u) {
        int c = threadIdx.x + u * 256;
        v[u] = (c < C) ? rowp[c] : -1e30f;
        mx = fmaxf(mx, v[u]);
    }
    red[threadIdx.x] = mx; __syncthreads();
    for (int s = 128; s > 0; s >>= 1) {
        if (threadIdx.x < s) red[threadIdx.x] = fmaxf(red[threadIdx.x], red[threadIdx.x + s]);
        __syncthreads();
    }
    float m = red[0];
    __syncthreads();

    float sum = 0.f;
#pragma unroll
    for (int u = 0; u < CPT; ++u) sum += __expf(v[u] - m);
    red[threadIdx.x] = sum; __syncthreads();
    for (int s = 128; s > 0; s >>= 1) {
        if (threadIdx.x < s) red[threadIdx.x] += red[threadIdx.x + s];
        __syncthreads();
    }
    float ls = m + logf(red[0]);

#pragma unroll
    for (int u = 0; u < CPT; ++u) {
        int c = threadIdx.x + u * 256;
        if (c < C) rowp[c] = v[u] - ls;
    }
}

// ----------------------------- entry -----------------------------

extern "C" void kernel_launch(void* const* d_in, const int* in_sizes, int n_in,
                              void* d_out, int out_size, void* d_ws, size_t ws_size,
                              hipStream_t stream) {
    const int N0 = 5000, K1 = 2000, K2 = 1000, K3 = 500, E = 80000, OUTC = 6890;
    const int Kp1 = 2048, Kp2 = 1024, Kp3 = 512, OUTCP = 6912;
    (void)in_sizes; (void)n_in; (void)out_size; (void)ws_size;

    const float* pos = (const float*)d_in[0];
    const int*   ei  = (const int*)d_in[1];
    const float* Wd0 = (const float*)d_in[2];  const float* bd0 = (const float*)d_in[3];
    const float* Wd1 = (const float*)d_in[4];  const float* bd1 = (const float*)d_in[5];
    const float* Wd2 = (const float*)d_in[6];  const float* bd2 = (const float*)d_in[7];
    const float* Wd3 = (const float*)d_in[8];  const float* bd3 = (const float*)d_in[9];
    const float* pw0 = (const float*)d_in[10];
    const float* pw1 = (const float*)d_in[11];
    const float* pw2 = (const float*)d_in[12];
    const float* Wu0 = (const float*)d_in[13]; const float* bu0 = (const float*)d_in[14];
    const float* Wu1 = (const float*)d_in[15]; const float* bu1 = (const float*)d_in[16];
    const float* Wu2 = (const float*)d_in[17]; const float* bu2 = (const float*)d_in[18];
    const float* W1  = (const float*)d_in[19]; const float* b1  = (const float*)d_in[20];
    const float* W2  = (const float*)d_in[21]; const float* b2  = (const float*)d_in[22];
    const float* W3  = (const float*)d_in[23]; const float* b3  = (const float*)d_in[24];

    float* w = (float*)d_ws;
    size_t off = 0;
    auto alloc = [&](size_t nel) { float* p = w + off; off += nel; return p; };

    // pool region: partials [0,13M) | G [13M,18.25M) | HT [18.25M,23.5M)
    // A2i aliases partials (pool-0); zhT/zlT overlap G (dense-GCN phase);
    // Ah/Al overlap partials (head phase only)
    float* pool = alloc(26220000);
    float* partials = pool;
    u16* G   = (u16*)(pool + 13000000);
    u16* HT  = (u16*)(pool + 18250000);
    u16* zhT = (u16*)(pool + 13000000);
    u16* zlT = (u16*)(pool + 13400000);
    u16* Ah  = (u16*)(pool);
    u16* Al  = (u16*)(pool + 400000);

    u16* adj1b  = (u16*)alloc(2097152);      // 2048 x 2048
    u16* adj1bT = (u16*)alloc(2097152);
    u16* adj2b  = (u16*)alloc(524288);       // 1024 x 1024
    u16* adj2bT = (u16*)alloc(524288);
    u16* adj3b  = (u16*)alloc(131072);       // 512 x 512
    u16* W3T    = (u16*)alloc(442368);       // 6912 x 128

    float* x0 = alloc((size_t)N0 * 128);
    float* x1 = alloc((size_t)K1 * 128);
    float* x2 = alloc((size_t)K2 * 128);
    float* xa = alloc((size_t)N0 * 128);
    float* xb = alloc((size_t)N0 * 128);
    float* xw = alloc((size_t)N0 * 128);
    float* dinv0 = alloc(N0); float* dinv1 = alloc(K1); float* dinv2 = alloc(K2); float* dinv3 = alloc(K3);
    float* scorev = alloc(N0);
    float* scv    = alloc(K1);
    int* perm0 = (int*)alloc(K1);
    int* perm1 = (int*)alloc(K2);
    int* perm2 = (int*)alloc(K3);
    int* rankpart = (int*)alloc(50048);
    int* rowcnt = (int*)alloc(5120);
    int* rowptr = (int*)alloc(5120);
    int* fillc  = (int*)alloc(5120);
    int* colsb  = (int*)alloc(80000);
    int* invb   = (int*)alloc(5120);

    auto launch_mm = [&](int SA, int SB, const u16* A0, const u16* A1, const u16* B0, const u16* B1,
                         float* Cc, const float* cbias, int M, int N, int Kpad,
                         int lda, int ldb, int ldc, size_t cstride, int Z) -> int {
        int kPerZ = CDIV(Kpad, Z * 32) * 32;
        int gz = CDIV(Kpad, kPerZ);
        dim3 g(CDIV(N, 128), CDIV(M, 128), gz);
        if (SA)      mm_nt<1, 0><<<g, 256, 0, stream>>>(A0, A1, B0, B1, Cc, cbias, M, N, lda, ldb, ldc, kPerZ, Kpad, cstride);
        else if (SB) mm_nt<0, 1><<<g, 256, 0, stream>>>(A0, A1, B0, B1, Cc, cbias, M, N, lda, ldb, ldc, kPerZ, Kpad, cstride);
        else         mm_nt<0, 0><<<g, 256, 0, stream>>>(A0, A1, B0, B1, Cc, cbias, M, N, lda, ldb, ldc, kPerZ, Kpad, cstride);
        return gz;
    };

    // dense gcn (levels 1-3)
    auto run_gcn = [&](const u16* adjb, int n, int Np,
                       const float* x, const float* W, const float* bias,
                       const float* dinv, int relu, float* y, int Z) {
        gemm64<<<dim3(2, CDIV(n, 64)), 256, 0, stream>>>(x, W, xw, n, 128, 128, 128, 128, 128, nullptr, 0);
        scale_split_k<<<dim3(Np / 32, 4), 256, 0, stream>>>(xw, dinv, zhT, zlT, n, Np);
        int gz = launch_mm(0, 1, adjb, nullptr, zhT, zlT, partials, nullptr,
                           Np, 128, Np, Np, Np, 128, (size_t)Np * 128, Z);
        reduce_gcn_post_k<<<n, 128, 0, stream>>>(partials, gz, Np, xw, dinv, bias, y, relu);
    };

    // sparse gcn (level 0)
    auto run_gcn_sp = [&](const float* x, int kin, const float* W, const float* bias, int relu, float* y) {
        gemm64<<<dim3(2, CDIV(N0, 64)), 256, 0, stream>>>(x, W, xw, N0, 128, kin, kin, 128, 128, nullptr, 0);
        spmm_gcn_k<<<N0, 128, 0, stream>>>(rowptr, colsb, dinv0, xw, bias, y, relu);
    };

    auto run_pool = [&](const float* x, int n, int Np, int kNew, int KpNew, const float* pw,
                        const u16* srcb, const u16* srcbT, u16* adjNew, int* perm, int Z) {
        score_k<<<n, 128, 0, stream>>>(x, pw, scorev);
        int nsl = CDIV(n, 512);
        rank_partial_k<<<dim3(CDIV(n, 256), nsl), 256, 0, stream>>>(scorev, n, rankpart);
        scatter_topk_k<<<CDIV(n, 256), 256, 0, stream>>>(scorev, rankpart, nsl, n, kNew, perm, scv);
        pool_x_k<<<kNew, 128, 0, stream>>>(xa, x, perm, scv);
        gather2_b_k<<<dim3(kNew, 2), 256, 0, stream>>>(srcb, srcbT, Np, perm, G, HT, Np);
        int gz = launch_mm(0, 0, G, nullptr, HT, nullptr, partials, nullptr,
                           KpNew, KpNew, Np, Np, Np, KpNew, (size_t)KpNew * KpNew, Z);
        reduce_pool_k<<<KpNew, 256, 0, stream>>>(partials, gz, kNew, KpNew, adjNew);
    };

    // ---- CSR of ALL edges (self included, multiplicity preserved), sorted rows; dinv0 ----
    hipMemsetAsync(rowcnt, 0, N0 * sizeof(int), stream);
    hipMemsetAsync(fillc, 0, N0 * sizeof(int), stream);
    csr_cnt_k<<<CDIV(E, 256), 256, 0, stream>>>(ei, E, rowcnt);
    prefix_k<<<1, 1024, 0, stream>>>(rowcnt, rowptr, N0);
    csr_fill_k<<<CDIV(E, 256), 256, 0, stream>>>(ei, E, rowptr, fillc, colsb);
    sortrows_k<<<CDIV(N0, 256), 256, 0, stream>>>(rowptr, colsb, N0);
    dinv_from_cnt_k<<<CDIV(N0, 256), 256, 0, stream>>>(rowcnt, dinv0, N0);

    // ---- initial GCN (sparse) ----
    run_gcn_sp(pos, 3, Wd0, bd0, 1, x0);

    // ---- down level 0: 5000 -> 2000 (sparse pool via SpGEMM) ----
    score_k<<<N0, 128, 0, stream>>>(x0, pw0, scorev);
    {
        int nsl = CDIV(N0, 512);
        rank_partial_k<<<dim3(CDIV(N0, 256), nsl), 256, 0, stream>>>(scorev, N0, rankpart);
        scatter_topk_k<<<CDIV(N0, 256), 256, 0, stream>>>(scorev, rankpart, nsl, N0, K1, perm0, scv);
    }
    pool_x_k<<<K1, 128, 0, stream>>>(xa, x0, perm0, scv);
    hipMemsetAsync(invb, 0xFF, N0 * sizeof(int), stream);
    inv_k<<<CDIV(K1, 256), 256, 0, stream>>>(perm0, K1, invb);
    int* A2i = (int*)partials;
    hipMemsetAsync(A2i, 0, (size_t)Kp1 * Kp1 * sizeof(int), stream);
    spgemm_k<<<K1, 256, 0, stream>>>(perm0, rowptr, colsb, invb, A2i, Kp1);
    conv_spg_k<<<Kp1, 256, 0, stream>>>(A2i, K1, Kp1, adj1b);

    transpose_b_k<<<dim3(Kp1 / 64, Kp1 / 64), 256, 0, stream>>>(adj1b, adj1bT, Kp1);
    rowsum_dinv_b_k<<<K1, 256, 0, stream>>>(adj1b, Kp1, Kp1, dinv1);
    run_gcn(adj1b, K1, Kp1, xa, Wd1, bd1, dinv1, 1, x1, 16);

    // ---- down level 1: 2000 -> 1000 (dense) ----
    run_pool(x1, K1, Kp1, K2, Kp2, pw1, adj1b, adj1bT, adj2b, perm1, 8);
    transpose_b_k<<<dim3(Kp2 / 64, Kp2 / 64), 256, 0, stream>>>(adj2b, adj2bT, Kp2);
    rowsum_dinv_b_k<<<K2, 256, 0, stream>>>(adj2b, Kp2, Kp2, dinv2);
    run_gcn(adj2b, K2, Kp2, xa, Wd2, bd2, dinv2, 1, x2, 16);

    // ---- down level 2: 1000 -> 500 (dense) ----
    run_pool(x2, K2, Kp2, K3, Kp3, pw2, adj2b, adj2bT, adj3b, perm2, 8);
    rowsum_dinv_b_k<<<K3, 256, 0, stream>>>(adj3b, Kp3, Kp3, dinv3);
    run_gcn(adj3b, K3, Kp3, xa, Wd3, bd3, dinv3, 1, xb, 8);                // xb: 500x128

    // ---- up i=0 (j=2) ----
    hipMemcpyAsync(xa, x2, (size_t)K2 * 128 * sizeof(float), hipMemcpyDeviceToDevice, stream);
    scatter_add_k<<<K3, 128, 0, stream>>>(xa, perm2, xb);
    run_gcn(adj2b, K2, Kp2, xa, Wu0, bu0, dinv2, 1, xb, 16);               // xb: 1000x128

    // ---- up i=1 (j=1) ----
    hipMemcpyAsync(xa, x1, (size_t)K1 * 128 * sizeof(float), hipMemcpyDeviceToDevice, stream);
    scatter_add_k<<<K2, 128, 0, stream>>>(xa, perm1, xb);
    run_gcn(adj1b, K1, Kp1, xa, Wu1, bu1, dinv1, 1, xb, 16);               // xb: 2000x128

    // ---- up i=2 (j=0), no relu (sparse) ----
    hipMemcpyAsync(xa, x0, (size_t)N0 * 128 * sizeof(float), hipMemcpyDeviceToDevice, stream);
    scatter_add_k<<<K1, 128, 0, stream>>>(xa, perm0, xb);
    run_gcn_sp(xa, 128, Wu2, bu2, 0, xb);                                  // xb: 5000x128

    // ---- MLP head (bias+relu fused in gemm64 epilogue) ----
    gemm64<<<dim3(2, CDIV(N0, 64)), 256, 0, stream>>>(xb, W1, xa, N0, 128, 128, 128, 128, 128, b1, 1);
    gemm64<<<dim3(2, CDIV(N0, 64)), 256, 0, stream>>>(xa, W2, xw, N0, 128, 128, 128, 128, 128, b2, 0);

    split_head_k<<<N0, 128, 0, stream>>>(xw, Ah, Al);
    convW3T_k<<<dim3(OUTCP / 64, 2), 256, 0, stream>>>(W3, W3T, OUTC, OUTCP);

    float* outp = (float*)d_out;
    launch_mm(1, 0, Ah, Al, W3T, nullptr, outp, b3, N0, OUTC, 128, 128, 128, OUTC, 0, 1);
    logsoftmax_k<<<N0, 256, 0, stream>>>(outp);
}